// Round 6
// baseline (743.757 us; speedup 1.0000x reference)
//
#include <hip/hip_runtime.h>

#define T 500
#define NB 256
#define VROWS 50001
#define EMB 200
#define KPAD 224
#define MPAD 50048
#define LOG2E 1.44269504f

typedef unsigned short u16;
typedef __attribute__((ext_vector_type(8))) __bf16 bf16x8;
typedef __attribute__((ext_vector_type(8))) short short8;
typedef __attribute__((ext_vector_type(4))) float f32x4;
typedef __attribute__((ext_vector_type(4))) u16 u16x4;
typedef __attribute__((ext_vector_type(4))) int i32x4;

__device__ __forceinline__ u16 f2bf(float x) {
  __bf16 h = (__bf16)x;
  return __builtin_bit_cast(u16, h);
}
__device__ __forceinline__ float bf2f(u16 b) {
  union { unsigned u; float f; } v; v.u = ((unsigned)b) << 16;
  return v.f;
}
__device__ __forceinline__ float rcp_(float x) { return __builtin_amdgcn_rcpf(x); }
__device__ __forceinline__ float ex2_(float x) { return __builtin_amdgcn_exp2f(x); }
// gate scale factors: sig(x)=rcp(1+exp2(-LOG2E*x)); tanh(x)=1-2*rcp(1+exp2(2*LOG2E*x))
__device__ __forceinline__ float gsc(int g) { return (g == 1) ? 2.f * LOG2E : -LOG2E; }

// ---------------------------------------------------------------- prep ------
__global__ void prep_kernel(const int* __restrict__ words, const int* __restrict__ caps,
                            const float* __restrict__ word_emb,
                            const float* __restrict__ cap_emb,
                            const float* __restrict__ Wfw, const float* __restrict__ bfw,
                            const float* __restrict__ Wbw, const float* __restrict__ bbw,
                            int* __restrict__ wordsT, int* __restrict__ capsT,
                            float* __restrict__ Cproj, u16* __restrict__ Apad,
                            u16* __restrict__ Bt) {
  const int S0 = NB * T;
  const int S1 = MPAD * (KPAD / 4);
  const int S2 = 2 * 512 * KPAD;
  const int S3 = 2 * 4 * 512;
  int tid = blockIdx.x * blockDim.x + threadIdx.x;
  int nthr = gridDim.x * blockDim.x;
  for (int i = tid; i < S0 + S1 + S2 + S3; i += nthr) {
    if (i < S0) {
      int b = i / T, t = i - b * T;
      wordsT[t * NB + b] = words[i];
      capsT[t * NB + b]  = caps[i];
    } else if (i < S0 + S1) {
      int idx = i - S0;
      int v = idx / (KPAD / 4), q = idx - v * (KPAD / 4);
      int k = q * 4;
      u16x4 o;
      if (v < VROWS && k < EMB) {
        const float* p = word_emb + (size_t)v * EMB + k;
        o[0] = f2bf(p[0]); o[1] = f2bf(p[1]); o[2] = f2bf(p[2]); o[3] = f2bf(p[3]);
      } else {
        o[0] = o[1] = o[2] = o[3] = 0;
      }
      *(u16x4*)(Apad + (size_t)v * KPAD + k) = o;
    } else if (i < S0 + S1 + S2) {
      int idx = i - S0 - S1;
      int d = idx / (512 * KPAD), rem = idx - d * (512 * KPAD);
      int colp = rem / KPAD, k = rem - colp * KPAD;
      const float* W = d ? Wbw : Wfw;
      int g = colp & 3, jj = colp >> 2;
      Bt[idx] = (k < EMB) ? f2bf(W[k * 512 + g * 128 + jj] * gsc(g)) : (u16)0;
    } else {
      int idx = i - S0 - S1 - S2;
      int dir = idx >> 11; int c = (idx >> 9) & 3; int colp = idx & 511;
      int j = colp >> 2, g = colp & 3;
      const float* W = dir ? Wbw : Wfw;
      const float* bias = dir ? bbw : bfw;
      float v = bias[g * 128 + j] + (g == 2 ? 1.f : 0.f);   // fold forget_bias
      #pragma unroll
      for (int cc = 0; cc < 3; ++cc)
        v += cap_emb[c * 3 + cc] * W[(200 + cc) * 512 + g * 128 + j];
      Cproj[idx] = v * gsc(g);
    }
  }
}

// ------------------------------------------------------------ Vproj GEMM ----
__global__ __launch_bounds__(256) void vproj_kernel(
    const u16* __restrict__ Apad, const u16* __restrict__ Bt,
    u16* __restrict__ Vfw, u16* __restrict__ Vbw) {
  const int mt = blockIdx.x, nt = blockIdx.y, dir = blockIdx.z;
  const u16* __restrict__ B = Bt + (size_t)dir * 512 * KPAD;
  u16* __restrict__ V = dir ? Vbw : Vfw;

  __shared__ u16 Al[2][128 * 32];
  __shared__ u16 Bl[2][128 * 32];

  const int tid = threadIdx.x;
  const int w = tid >> 6, l = tid & 63;
  const int la = l & 15, lb = l >> 4;
  const int m0 = mt * 128, n0 = nt * 128;

  auto stage = [&](int buf, int ks) {
    int k0 = ks * 32;
    #pragma unroll
    for (int h = 0; h < 2; ++h) {
      int c = w * 128 + h * 64 + l;
      int row = c >> 2, kq = c & 3;
      const u16* ga = Apad + (size_t)(m0 + row) * KPAD + k0 + kq * 8;
      __builtin_amdgcn_global_load_lds(
          (const __attribute__((address_space(1))) void*)ga,
          (__attribute__((address_space(3))) void*)&Al[buf][(w * 128 + h * 64) * 8],
          16, 0, 0);
      const u16* gb = B + (size_t)(n0 + row) * KPAD + k0 + kq * 8;
      __builtin_amdgcn_global_load_lds(
          (const __attribute__((address_space(1))) void*)gb,
          (__attribute__((address_space(3))) void*)&Bl[buf][(w * 128 + h * 64) * 8],
          16, 0, 0);
    }
  };

  f32x4 z = {0.f, 0.f, 0.f, 0.f};
  f32x4 acc[4][4] = {{z,z,z,z},{z,z,z,z},{z,z,z,z},{z,z,z,z}};
  const int wr = w >> 1, wc = w & 1;

  stage(0, 0);
  __syncthreads();
  #pragma unroll 1
  for (int ks = 0; ks < 7; ++ks) {
    int cur = ks & 1;
    if (ks < 6) stage(cur ^ 1, ks + 1);
    bf16x8 af[4], bfr[4];
    #pragma unroll
    for (int m = 0; m < 4; ++m)
      af[m] = *(const bf16x8*)&Al[cur][(wr * 64 + m * 16 + la) * 32 + lb * 8];
    #pragma unroll
    for (int n = 0; n < 4; ++n)
      bfr[n] = *(const bf16x8*)&Bl[cur][(wc * 64 + n * 16 + la) * 32 + lb * 8];
    #pragma unroll
    for (int m = 0; m < 4; ++m)
      #pragma unroll
      for (int n = 0; n < 4; ++n)
        acc[m][n] = __builtin_amdgcn_mfma_f32_16x16x32_bf16(af[m], bfr[n], acc[m][n], 0, 0, 0);
    __syncthreads();
  }

  #pragma unroll
  for (int m = 0; m < 4; ++m) {
    #pragma unroll
    for (int n = 0; n < 4; ++n) {
      #pragma unroll
      for (int r = 0; r < 4; ++r) {
        int v = m0 + wr * 64 + m * 16 + lb * 4 + r;
        int colp = n0 + wc * 64 + n * 16 + la;
        V[(size_t)v * 512 + colp] = f2bf(acc[m][n][r]);
      }
    }
  }
}

// ------------------------------------------------------------ LSTM ----------
// 4 waves/block (256 thr), 32 blocks.  Each wave owns 32 gate-cols (2 j-groups).
// hbuf [2][16][128] u16, XOR-swizzled: u16 idx ^= (row&7)<<3 on write and read.
// Barrier WITHOUT vmcnt drain.
template <int PAR>
__device__ __forceinline__ void lstm_step(
    int t, int dir, int b0, int la, int lb, int w,
    const int* __restrict__ wordsT, const int* __restrict__ capsT,
    const u16* __restrict__ V, const float* __restrict__ Cp,
    const bf16x8 (&bfrag)[4][2][4], u16* __restrict__ hbuf,
    u16x4 (&vw_c)[2][4], f32x4 (&cp_c)[2][4],  // data for t (consume)
    i32x4& wi_c, i32x4& ci_c,                  // slot t: reload with idx(t+4)
    i32x4& wi_g, i32x4& ci_g,                  // idx(t+2) (ready)
    u16x4 (&vw_g)[2][4], f32x4 (&cp_g)[2][4],  // gather target for t+2
    f32x4 (&cst)[2], f32x4 (&hl)[2]) {
  // A fragments (h_prev) from swizzled LDS — issue immediately after barrier
  const u16* hb = hbuf + PAR * 2048;
  const int swz = (la & 7) << 3;
  bf16x8 afr[4];
  #pragma unroll
  for (int kk = 0; kk < 4; ++kk)
    afr[kk] = *(const bf16x8*)(hb + ((la * 128 + kk * 32 + lb * 8) ^ swz));

  // reload indices for t+4 into this step's (now free) slot
  {
    int ts = t + 4; if (ts > T - 1) ts = T - 1;
    int tt = dir ? (T - 1 - ts) : ts;
    wi_c = *(const i32x4*)(wordsT + tt * NB + b0 + lb * 4);
    ci_c = *(const i32x4*)(capsT + tt * NB + b0 + lb * 4);
  }
  // issue gathers for t+2 (2-step prefetch distance)
  #pragma unroll
  for (int jg = 0; jg < 2; ++jg) {
    int jc = w * 32 + jg * 16 + la;
    #pragma unroll
    for (int r = 0; r < 4; ++r) {
      vw_g[jg][r] = *(const u16x4*)(V + (size_t)wi_g[r] * 512 + jc * 4);
      cp_g[jg][r] = *(const f32x4*)(Cp + ci_g[r] * 512 + jc * 4);
    }
  }

  // init accumulators with x-projection (+cap+bias), pre-scaled
  f32x4 acc[4][2];
  #pragma unroll
  for (int jg = 0; jg < 2; ++jg)
    #pragma unroll
    for (int r = 0; r < 4; ++r) {
      acc[0][jg][r] = bf2f(vw_c[jg][r][0]) + cp_c[jg][r][0];
      acc[1][jg][r] = bf2f(vw_c[jg][r][1]) + cp_c[jg][r][1];
      acc[2][jg][r] = bf2f(vw_c[jg][r][2]) + cp_c[jg][r][2];
      acc[3][jg][r] = bf2f(vw_c[jg][r][3]) + cp_c[jg][r][3];
    }
  // gates += h_prev @ Wh (pre-scaled)
  #pragma unroll
  for (int kk = 0; kk < 4; ++kk)
    #pragma unroll
    for (int g = 0; g < 4; ++g)
      #pragma unroll
      for (int jg = 0; jg < 2; ++jg)
        acc[g][jg] = __builtin_amdgcn_mfma_f32_16x16x32_bf16(
            afr[kk], bfrag[g][jg][kk], acc[g][jg], 0, 0, 0);

  // cell update; write h_new to other buffer (swizzled)
  u16* ho = hbuf + (PAR ^ 1) * 2048;
  #pragma unroll
  for (int jg = 0; jg < 2; ++jg)
    #pragma unroll
    for (int r = 0; r < 4; ++r) {
      float ig = rcp_(1.f + ex2_(acc[0][jg][r]));
      float tj = 1.f - 2.f * rcp_(1.f + ex2_(acc[1][jg][r]));
      float fg = rcp_(1.f + ex2_(acc[2][jg][r]));
      float cn = fg * cst[jg][r] + ig * tj;
      cst[jg][r] = cn;
      float og = rcp_(1.f + ex2_(acc[3][jg][r]));
      float hn = og * (1.f - 2.f * rcp_(1.f + ex2_(2.f * LOG2E * cn)));
      hl[jg][r] = hn;
      int row = lb * 4 + r;
      int col = w * 32 + jg * 16 + la;
      ho[(row * 128 + col) ^ ((row & 7) << 3)] = f2bf(hn);
    }
  // LDS-only drain + raw barrier: vmcnt NOT drained, gathers stay in flight
  __builtin_amdgcn_sched_barrier(0);
  asm volatile("s_waitcnt lgkmcnt(0)");
  __builtin_amdgcn_s_barrier();
  __builtin_amdgcn_sched_barrier(0);
}

__global__ __launch_bounds__(256, 1) void lstm_kernel(
    const int* __restrict__ wordsT, const int* __restrict__ capsT,
    const u16* __restrict__ Vfw, const u16* __restrict__ Vbw,
    const float* __restrict__ CprojAll, const float* __restrict__ Wfw,
    const float* __restrict__ Wbw, float* __restrict__ rnn) {
  const int dir = blockIdx.x & 1;
  const int chunk = blockIdx.x >> 1;
  const int b0 = chunk * 16;
  const u16* __restrict__ V = dir ? Vbw : Vfw;
  const float* __restrict__ Cp = CprojAll + dir * 4 * 512;
  const float* __restrict__ W = dir ? Wbw : Wfw;

  const int tid = threadIdx.x;
  const int w = tid >> 6, l = tid & 63, la = l & 15, lb = l >> 4;

  // Wh fragments (pre-scaled): col = g*128 + w*32 + jg*16 + la, k = kk*32+lb*8+r
  bf16x8 bfrag[4][2][4];
  #pragma unroll
  for (int g = 0; g < 4; ++g)
    #pragma unroll
    for (int jg = 0; jg < 2; ++jg)
      #pragma unroll
      for (int kk = 0; kk < 4; ++kk) {
        short8 t8;
        #pragma unroll
        for (int r = 0; r < 8; ++r) {
          int k = kk * 32 + lb * 8 + r;
          t8[r] = (short)f2bf(W[(203 + k) * 512 + g * 128 + w * 32 + jg * 16 + la] * gsc(g));
        }
        bfrag[g][jg][kk] = __builtin_bit_cast(bf16x8, t8);
      }

  __shared__ u16 hbuf[2 * 16 * 128];
  for (int i = tid; i < 2 * 16 * 128; i += 256) hbuf[i] = 0;

  f32x4 cst[2] = {{0.f,0.f,0.f,0.f},{0.f,0.f,0.f,0.f}};
  f32x4 hl[2]  = {{0.f,0.f,0.f,0.f},{0.f,0.f,0.f,0.f}};

  // 4-slot prefetch ring
  i32x4 wiA, ciA, wiB, ciB, wiC, ciC, wiD, ciD;
  u16x4 vwA[2][4], vwB[2][4], vwC[2][4], vwD[2][4];
  f32x4 cpA[2][4], cpB[2][4], cpC[2][4], cpD[2][4];
  {
    int t0 = dir ? (T - 1) : 0;
    int t1 = dir ? (T - 2) : 1;
    int t2 = dir ? (T - 3) : 2;
    int t3 = dir ? (T - 4) : 3;
    wiA = *(const i32x4*)(wordsT + t0 * NB + b0 + lb * 4);
    ciA = *(const i32x4*)(capsT + t0 * NB + b0 + lb * 4);
    wiB = *(const i32x4*)(wordsT + t1 * NB + b0 + lb * 4);
    ciB = *(const i32x4*)(capsT + t1 * NB + b0 + lb * 4);
    wiC = *(const i32x4*)(wordsT + t2 * NB + b0 + lb * 4);
    ciC = *(const i32x4*)(capsT + t2 * NB + b0 + lb * 4);
    wiD = *(const i32x4*)(wordsT + t3 * NB + b0 + lb * 4);
    ciD = *(const i32x4*)(capsT + t3 * NB + b0 + lb * 4);
  }
  #pragma unroll
  for (int jg = 0; jg < 2; ++jg) {
    int jc = w * 32 + jg * 16 + la;
    #pragma unroll
    for (int r = 0; r < 4; ++r) {
      vwA[jg][r] = *(const u16x4*)(V + (size_t)wiA[r] * 512 + jc * 4);
      cpA[jg][r] = *(const f32x4*)(Cp + ciA[r] * 512 + jc * 4);
      vwB[jg][r] = *(const u16x4*)(V + (size_t)wiB[r] * 512 + jc * 4);
      cpB[jg][r] = *(const f32x4*)(Cp + ciB[r] * 512 + jc * 4);
    }
  }
  __syncthreads();

  #pragma unroll 1
  for (int tq = 0; tq < T / 4; ++tq) {
    int t0 = 4 * tq;
    lstm_step<0>(t0,     dir, b0, la, lb, w, wordsT, capsT, V, Cp, bfrag, hbuf,
                 vwA, cpA, wiA, ciA, wiC, ciC, vwC, cpC, cst, hl);
    lstm_step<1>(t0 + 1, dir, b0, la, lb, w, wordsT, capsT, V, Cp, bfrag, hbuf,
                 vwB, cpB, wiB, ciB, wiD, ciD, vwD, cpD, cst, hl);
    lstm_step<0>(t0 + 2, dir, b0, la, lb, w, wordsT, capsT, V, Cp, bfrag, hbuf,
                 vwC, cpC, wiC, ciC, wiA, ciA, vwA, cpA, cst, hl);
    lstm_step<1>(t0 + 3, dir, b0, la, lb, w, wordsT, capsT, V, Cp, bfrag, hbuf,
                 vwD, cpD, wiD, ciD, wiB, ciB, vwB, cpB, cst, hl);
  }

  #pragma unroll
  for (int jg = 0; jg < 2; ++jg)
    #pragma unroll
    for (int r = 0; r < 4; ++r)
      rnn[(size_t)(b0 + lb * 4 + r) * 256 + dir * 128 + w * 32 + jg * 16 + la] = hl[jg][r];
}

// ------------------------------------------------------------ head ----------
__global__ void head_kernel(const float* __restrict__ rnn, const float* __restrict__ W1,
                            const float* __restrict__ b1, const float* __restrict__ W2,
                            const float* __restrict__ b2, float* __restrict__ out) {
  int b = blockIdx.x;
  int jj = threadIdx.x;  // 64 threads
  __shared__ float d1[64];
  float acc = b1[jj];
  const float* r = rnn + b * 256;
  #pragma unroll 4
  for (int k = 0; k < 256; ++k) acc += r[k] * W1[k * 64 + jj];
  d1[jj] = acc > 0.f ? acc : (__expf(acc) - 1.f);
  __syncthreads();
  if (jj < 6) {
    float a2 = b2[jj];
    #pragma unroll 8
    for (int k = 0; k < 64; ++k) a2 += d1[k] * W2[k * 6 + jj];
    out[b * 6 + jj] = rcp_(1.f + __expf(-a2));
  }
}

// ------------------------------------------------------------ launch --------
extern "C" void kernel_launch(void* const* d_in, const int* in_sizes, int n_in,
                              void* d_out, int out_size, void* d_ws, size_t ws_size,
                              hipStream_t stream) {
  (void)in_sizes; (void)n_in; (void)out_size; (void)ws_size;
  const int*   words    = (const int*)  d_in[0];
  const int*   caps     = (const int*)  d_in[1];
  const float* word_emb = (const float*)d_in[2];
  const float* cap_emb  = (const float*)d_in[3];
  const float* Wfw      = (const float*)d_in[4];
  const float* bfw      = (const float*)d_in[5];
  const float* Wbw      = (const float*)d_in[6];
  const float* bbw      = (const float*)d_in[7];
  const float* W1       = (const float*)d_in[8];
  const float* b1       = (const float*)d_in[9];
  const float* W2       = (const float*)d_in[10];
  const float* b2       = (const float*)d_in[11];
  float* out = (float*)d_out;

  char* base = (char*)d_ws;
  size_t off = 0;
  auto alloc = [&](size_t bytes) {
    char* q = base + off;
    off = (off + bytes + 255) & ~(size_t)255;
    return q;
  };
  u16*   Vfw    = (u16*)  alloc((size_t)MPAD * 512 * 2);
  u16*   Vbw    = (u16*)  alloc((size_t)MPAD * 512 * 2);
  u16*   Apad   = (u16*)  alloc((size_t)MPAD * KPAD * 2);
  u16*   Bt     = (u16*)  alloc((size_t)2 * 512 * KPAD * 2);
  int*   wordsT = (int*)  alloc((size_t)T * NB * 4);
  int*   capsT  = (int*)  alloc((size_t)T * NB * 4);
  float* Cproj  = (float*)alloc((size_t)2 * 4 * 512 * 4);
  float* rnn    = (float*)alloc((size_t)256 * 256 * 4);

  hipLaunchKernelGGL(prep_kernel, dim3(2048), dim3(256), 0, stream,
                     words, caps, word_emb, cap_emb, Wfw, bfw, Wbw, bbw,
                     wordsT, capsT, Cproj, Apad, Bt);
  hipLaunchKernelGGL(vproj_kernel, dim3(MPAD / 128, 4, 2), dim3(256), 0, stream,
                     Apad, Bt, Vfw, Vbw);
  hipLaunchKernelGGL(lstm_kernel, dim3(32), dim3(256), 0, stream,
                     wordsT, capsT, Vfw, Vbw, Cproj, Wfw, Wbw, rnn);
  hipLaunchKernelGGL(head_kernel, dim3(256), dim3(64), 0, stream,
                     rnn, W1, b1, W2, b2, out);
}

// Round 7
// 700.694 us; speedup vs baseline: 1.0615x; 1.0615x over previous
//
#include <hip/hip_runtime.h>

#define T 500
#define NB 256
#define VROWS 50001
#define EMB 200
#define KPAD 224
#define LOG2E 1.44269504f

typedef unsigned short u16;
typedef __attribute__((ext_vector_type(8))) __bf16 bf16x8;
typedef __attribute__((ext_vector_type(8))) short short8;
typedef __attribute__((ext_vector_type(8))) u16 u16x8;
typedef __attribute__((ext_vector_type(4))) float f32x4;
typedef __attribute__((ext_vector_type(4))) u16 u16x4;

__device__ __forceinline__ u16 f2bf(float x) {
  __bf16 h = (__bf16)x;
  return __builtin_bit_cast(u16, h);
}
__device__ __forceinline__ float bf2f(u16 b) {
  union { unsigned u; float f; } v; v.u = ((unsigned)b) << 16;
  return v.f;
}
__device__ __forceinline__ float rcp_(float x) { return __builtin_amdgcn_rcpf(x); }
__device__ __forceinline__ float ex2_(float x) { return __builtin_amdgcn_exp2f(x); }
// gate scales: sig(x)=rcp(1+exp2(-LOG2E*x)); tanh(x)=1-2*rcp(1+exp2(2*LOG2E*x))
__device__ __forceinline__ float gsc(int g) { return (g == 1) ? 2.f * LOG2E : -LOG2E; }

// ---------------------------------------------------------------- prep ------
// Bt[dir][colp][KPAD] bf16 (pre-scaled Wx^T, colp = j*4+g), Cproj[dir][cap][colp]
// f32 (pre-scaled bias + forget_bias + cap one-hot part).
__global__ void prep_kernel(const float* __restrict__ cap_emb,
                            const float* __restrict__ Wfw, const float* __restrict__ bfw,
                            const float* __restrict__ Wbw, const float* __restrict__ bbw,
                            float* __restrict__ Cproj, u16* __restrict__ Bt) {
  const int S2 = 2 * 512 * KPAD;
  const int S3 = 2 * 4 * 512;
  int tid = blockIdx.x * blockDim.x + threadIdx.x;
  int nthr = gridDim.x * blockDim.x;
  for (int i = tid; i < S2 + S3; i += nthr) {
    if (i < S2) {
      int d = i / (512 * KPAD), rem = i - d * (512 * KPAD);
      int colp = rem / KPAD, k = rem - colp * KPAD;
      const float* W = d ? Wbw : Wfw;
      int g = colp & 3, jj = colp >> 2;
      Bt[i] = (k < EMB) ? f2bf(W[k * 512 + g * 128 + jj] * gsc(g)) : (u16)0;
    } else {
      int idx = i - S2;
      int dir = idx >> 11; int c = (idx >> 9) & 3; int colp = idx & 511;
      int j = colp >> 2, g = colp & 3;
      const float* W = dir ? Wbw : Wfw;
      const float* bias = dir ? bbw : bfw;
      float v = bias[g * 128 + j] + (g == 2 ? 1.f : 0.f);   // fold forget_bias
      #pragma unroll
      for (int cc = 0; cc < 3; ++cc)
        v += cap_emb[c * 3 + cc] * W[(200 + cc) * 512 + g * 128 + j];
      Cproj[idx] = v * gsc(g);
    }
  }
}

// ------------------------------------------------------------ XP GEMM -------
// XP[dir][t][b][colp] = bf16( word_emb[words[b][t],:] @ Wx_scaled[:,colp]
//                             + Cproj[dir][caps[b][t]][colp] )
// M = 128000 token-rows (t = m>>8 uniform per block, b = m&255), N = 512, K = 224.
__global__ __launch_bounds__(256) void xproj_kernel(
    const int* __restrict__ words, const int* __restrict__ caps,
    const float* __restrict__ word_emb, const u16* __restrict__ Bt,
    const float* __restrict__ Cproj, u16* __restrict__ XP) {
  const int mt = blockIdx.x, nt = blockIdx.y, dir = blockIdx.z;
  const u16* __restrict__ B = Bt + (size_t)dir * 512 * KPAD;
  const float* __restrict__ Cb = Cproj + dir * 4 * 512;
  u16* __restrict__ xp = XP + (size_t)dir * T * NB * 512;

  __shared__ u16 As[2][128 * 32];
  __shared__ u16 Bs[2][128 * 32];

  const int tid = threadIdx.x;
  const int w = tid >> 6, l = tid & 63;
  const int la = l & 15, lb = l >> 4;
  const int m0 = mt * 128, n0 = nt * 128;
  const int tblk = m0 >> 8;                 // block-uniform timestep

  // A staging assignment: row ar = tid>>1 (0..127), k-half ah = tid&1 (16 k)
  const int ar = tid >> 1, ah = tid & 1;
  const int ab = (m0 & 255) + ar;           // batch row
  const int aword = words[ab * T + tblk];
  const float* __restrict__ aemb = word_emb + (size_t)aword * EMB;

  auto stageA = [&](int buf, int ks) {
    int kbase = ks * 32 + ah * 16;
    u16x8 lo, hi;
    #pragma unroll
    for (int q = 0; q < 4; ++q) {
      int k = kbase + q * 4;
      f32x4 v;
      if (k < EMB) v = *(const f32x4*)(aemb + k);
      else v = f32x4{0.f, 0.f, 0.f, 0.f};
      u16 b0 = f2bf(v[0]), b1 = f2bf(v[1]), b2 = f2bf(v[2]), b3 = f2bf(v[3]);
      if (q < 2) { lo[q*4+0]=b0; lo[q*4+1]=b1; lo[q*4+2]=b2; lo[q*4+3]=b3; }
      else { int qq=q-2; hi[qq*4+0]=b0; hi[qq*4+1]=b1; hi[qq*4+2]=b2; hi[qq*4+3]=b3; }
    }
    *(u16x8*)&As[buf][ar * 32 + ah * 16]     = lo;
    *(u16x8*)&As[buf][ar * 32 + ah * 16 + 8] = hi;
  };
  auto stageB = [&](int buf, int ks) {
    int k0 = ks * 32;
    #pragma unroll
    for (int h = 0; h < 2; ++h) {
      int c = w * 128 + h * 64 + l;
      int row = c >> 2, kq = c & 3;
      const u16* gb = B + (size_t)(n0 + row) * KPAD + k0 + kq * 8;
      __builtin_amdgcn_global_load_lds(
          (const __attribute__((address_space(1))) void*)gb,
          (__attribute__((address_space(3))) void*)&Bs[buf][(w * 128 + h * 64) * 8],
          16, 0, 0);
    }
  };

  f32x4 z = {0.f, 0.f, 0.f, 0.f};
  f32x4 acc[4][4] = {{z,z,z,z},{z,z,z,z},{z,z,z,z},{z,z,z,z}};
  const int wr = w >> 1, wc = w & 1;

  stageA(0, 0); stageB(0, 0);
  __syncthreads();
  #pragma unroll 1
  for (int ks = 0; ks < 7; ++ks) {
    int cur = ks & 1;
    if (ks < 6) { stageA(cur ^ 1, ks + 1); stageB(cur ^ 1, ks + 1); }
    bf16x8 af[4], bfr[4];
    #pragma unroll
    for (int m = 0; m < 4; ++m)
      af[m] = *(const bf16x8*)&As[cur][(wr * 64 + m * 16 + la) * 32 + lb * 8];
    #pragma unroll
    for (int n = 0; n < 4; ++n)
      bfr[n] = *(const bf16x8*)&Bs[cur][(wc * 64 + n * 16 + la) * 32 + lb * 8];
    #pragma unroll
    for (int m = 0; m < 4; ++m)
      #pragma unroll
      for (int n = 0; n < 4; ++n)
        acc[m][n] = __builtin_amdgcn_mfma_f32_16x16x32_bf16(af[m], bfr[n], acc[m][n], 0, 0, 0);
    __syncthreads();
  }

  #pragma unroll
  for (int m = 0; m < 4; ++m) {
    #pragma unroll
    for (int r = 0; r < 4; ++r) {
      int b = (m0 & 255) + wr * 64 + m * 16 + lb * 4 + r;
      int cap = caps[b * T + tblk];
      const float* cbr = Cb + cap * 512;
      u16* op = xp + ((size_t)tblk * NB + b) * 512;
      #pragma unroll
      for (int n = 0; n < 4; ++n) {
        int colp = n0 + wc * 64 + n * 16 + la;
        op[colp] = f2bf(acc[m][n][r] + cbr[colp]);
      }
    }
  }
}

// ------------------------------------------------------------ LSTM ----------
// 8 waves (512 thr), 32 blocks (16 batch rows x 2 dir).  Per step the wave
// reads its 4 xp vectors (linear addresses), 4 ds_read_b128 of h (swizzled),
// 16 MFMA, elementwise, h write, LDS-only barrier (vmcnt stays in flight).
template <int PAR>
__device__ __forceinline__ void lstm_step(
    int t, int dir, int la, int lb, int j,
    const u16* __restrict__ xpd, int voff0, int voff1, int voff2, int voff3,
    const bf16x8 (&bfrag)[4][4], u16* __restrict__ hbuf,
    u16x4 (&xc)[4],            // data for t (consume)
    u16x4 (&xg)[4],            // load target for t+2
    f32x4& cst, f32x4& hl) {
  // A fragments (h_prev) from swizzled LDS — first after barrier
  const u16* hb = hbuf + PAR * 2048;
  const int swz = (la & 7) << 3;
  bf16x8 afr[4];
  #pragma unroll
  for (int kk = 0; kk < 4; ++kk)
    afr[kk] = *(const bf16x8*)(hb + ((la * 128 + kk * 32 + lb * 8) ^ swz));

  // issue xp loads for t+2 (linear stream, 2-step prefetch)
  {
    int ts = t + 2; if (ts > T - 1) ts = T - 1;
    int tt = dir ? (T - 1 - ts) : ts;
    const u16* p = xpd + (size_t)tt * (NB * 512);
    xg[0] = *(const u16x4*)(p + voff0);
    xg[1] = *(const u16x4*)(p + voff1);
    xg[2] = *(const u16x4*)(p + voff2);
    xg[3] = *(const u16x4*)(p + voff3);
  }

  // accumulators = x-projection (pre-scaled, bias+cap folded)
  f32x4 acc0, acc1, acc2, acc3;
  #pragma unroll
  for (int r = 0; r < 4; ++r) {
    acc0[r] = bf2f(xc[r][0]);
    acc1[r] = bf2f(xc[r][1]);
    acc2[r] = bf2f(xc[r][2]);
    acc3[r] = bf2f(xc[r][3]);
  }
  // gates += h_prev @ Wh (pre-scaled)
  __builtin_amdgcn_s_setprio(1);
  #pragma unroll
  for (int kk = 0; kk < 4; ++kk) {
    acc0 = __builtin_amdgcn_mfma_f32_16x16x32_bf16(afr[kk], bfrag[0][kk], acc0, 0, 0, 0);
    acc1 = __builtin_amdgcn_mfma_f32_16x16x32_bf16(afr[kk], bfrag[1][kk], acc1, 0, 0, 0);
    acc2 = __builtin_amdgcn_mfma_f32_16x16x32_bf16(afr[kk], bfrag[2][kk], acc2, 0, 0, 0);
    acc3 = __builtin_amdgcn_mfma_f32_16x16x32_bf16(afr[kk], bfrag[3][kk], acc3, 0, 0, 0);
  }
  __builtin_amdgcn_s_setprio(0);
  // cell update; write h_new to other buffer (swizzled)
  u16* ho = hbuf + (PAR ^ 1) * 2048;
  #pragma unroll
  for (int r = 0; r < 4; ++r) {
    float ig = rcp_(1.f + ex2_(acc0[r]));
    float tj = 1.f - 2.f * rcp_(1.f + ex2_(acc1[r]));
    float fg = rcp_(1.f + ex2_(acc2[r]));
    float cn = fg * cst[r] + ig * tj;
    cst[r] = cn;
    float og = rcp_(1.f + ex2_(acc3[r]));
    float hn = og * (1.f - 2.f * rcp_(1.f + ex2_(2.f * LOG2E * cn)));
    hl[r] = hn;
    int row = lb * 4 + r;
    ho[(row * 128 + j) ^ ((row & 7) << 3)] = f2bf(hn);
  }
  // LDS-only drain + raw barrier: vmcnt NOT drained, xp loads stay in flight
  __builtin_amdgcn_sched_barrier(0);
  asm volatile("s_waitcnt lgkmcnt(0)");
  __builtin_amdgcn_s_barrier();
  __builtin_amdgcn_sched_barrier(0);
}

__global__ __launch_bounds__(512, 1) void lstm_kernel(
    const u16* __restrict__ XP, const float* __restrict__ Wfw,
    const float* __restrict__ Wbw, float* __restrict__ rnn) {
  const int dir = blockIdx.x & 1;
  const int chunk = blockIdx.x >> 1;
  const int b0 = chunk * 16;
  const u16* __restrict__ xpd = XP + (size_t)dir * T * NB * 512;
  const float* __restrict__ W = dir ? Wbw : Wfw;

  const int tid = threadIdx.x;
  const int w = tid >> 6, l = tid & 63, la = l & 15, lb = l >> 4;
  const int j = w * 16 + la;

  // per-lane xp offsets (u16 units) for rows b0+lb*4+r, cols j*4..j*4+3
  const int voff0 = (b0 + lb * 4 + 0) * 512 + j * 4;
  const int voff1 = (b0 + lb * 4 + 1) * 512 + j * 4;
  const int voff2 = (b0 + lb * 4 + 2) * 512 + j * 4;
  const int voff3 = (b0 + lb * 4 + 3) * 512 + j * 4;

  // Wh fragments (pre-scaled): col = g*128 + j, k = kk*32 + lb*8 + r
  bf16x8 bfrag[4][4];
  #pragma unroll
  for (int g = 0; g < 4; ++g) {
    #pragma unroll
    for (int kk = 0; kk < 4; ++kk) {
      short8 t8;
      #pragma unroll
      for (int r = 0; r < 8; ++r) {
        int k = kk * 32 + lb * 8 + r;
        t8[r] = (short)f2bf(W[(203 + k) * 512 + g * 128 + j] * gsc(g));
      }
      bfrag[g][kk] = __builtin_bit_cast(bf16x8, t8);
    }
  }

  __shared__ u16 hbuf[2 * 16 * 128];
  for (int i = tid; i < 2 * 16 * 128; i += 512) hbuf[i] = 0;

  f32x4 cst = {0.f, 0.f, 0.f, 0.f};
  f32x4 hl  = {0.f, 0.f, 0.f, 0.f};

  // 4-slot xp ring
  u16x4 xA[4], xB[4], xC[4], xD[4];
  {
    int tt0 = dir ? (T - 1) : 0;
    int tt1 = dir ? (T - 2) : 1;
    const u16* p0 = xpd + (size_t)tt0 * (NB * 512);
    const u16* p1 = xpd + (size_t)tt1 * (NB * 512);
    xA[0] = *(const u16x4*)(p0 + voff0); xA[1] = *(const u16x4*)(p0 + voff1);
    xA[2] = *(const u16x4*)(p0 + voff2); xA[3] = *(const u16x4*)(p0 + voff3);
    xB[0] = *(const u16x4*)(p1 + voff0); xB[1] = *(const u16x4*)(p1 + voff1);
    xB[2] = *(const u16x4*)(p1 + voff2); xB[3] = *(const u16x4*)(p1 + voff3);
  }
  __syncthreads();

  #pragma unroll 1
  for (int tq = 0; tq < T / 4; ++tq) {
    int t0 = 4 * tq;
    lstm_step<0>(t0,     dir, la, lb, j, xpd, voff0, voff1, voff2, voff3,
                 bfrag, hbuf, xA, xC, cst, hl);
    lstm_step<1>(t0 + 1, dir, la, lb, j, xpd, voff0, voff1, voff2, voff3,
                 bfrag, hbuf, xB, xD, cst, hl);
    lstm_step<0>(t0 + 2, dir, la, lb, j, xpd, voff0, voff1, voff2, voff3,
                 bfrag, hbuf, xC, xA, cst, hl);
    lstm_step<1>(t0 + 3, dir, la, lb, j, xpd, voff0, voff1, voff2, voff3,
                 bfrag, hbuf, xD, xB, cst, hl);
  }

  #pragma unroll
  for (int r = 0; r < 4; ++r)
    rnn[(size_t)(b0 + lb * 4 + r) * 256 + dir * 128 + j] = hl[r];
}

// ------------------------------------------------------------ head ----------
__global__ void head_kernel(const float* __restrict__ rnn, const float* __restrict__ W1,
                            const float* __restrict__ b1, const float* __restrict__ W2,
                            const float* __restrict__ b2, float* __restrict__ out) {
  int b = blockIdx.x;
  int jj = threadIdx.x;  // 64 threads
  __shared__ float d1[64];
  float acc = b1[jj];
  const float* r = rnn + b * 256;
  #pragma unroll 4
  for (int k = 0; k < 256; ++k) acc += r[k] * W1[k * 64 + jj];
  d1[jj] = acc > 0.f ? acc : (__expf(acc) - 1.f);
  __syncthreads();
  if (jj < 6) {
    float a2 = b2[jj];
    #pragma unroll 8
    for (int k = 0; k < 64; ++k) a2 += d1[k] * W2[k * 6 + jj];
    out[b * 6 + jj] = rcp_(1.f + __expf(-a2));
  }
}

// ------------------------------------------------------------ launch --------
extern "C" void kernel_launch(void* const* d_in, const int* in_sizes, int n_in,
                              void* d_out, int out_size, void* d_ws, size_t ws_size,
                              hipStream_t stream) {
  (void)in_sizes; (void)n_in; (void)out_size; (void)ws_size;
  const int*   words    = (const int*)  d_in[0];
  const int*   caps     = (const int*)  d_in[1];
  const float* word_emb = (const float*)d_in[2];
  const float* cap_emb  = (const float*)d_in[3];
  const float* Wfw      = (const float*)d_in[4];
  const float* bfw      = (const float*)d_in[5];
  const float* Wbw      = (const float*)d_in[6];
  const float* bbw      = (const float*)d_in[7];
  const float* W1       = (const float*)d_in[8];
  const float* b1       = (const float*)d_in[9];
  const float* W2       = (const float*)d_in[10];
  const float* b2       = (const float*)d_in[11];
  float* out = (float*)d_out;

  char* base = (char*)d_ws;
  size_t off = 0;
  auto alloc = [&](size_t bytes) {
    char* q = base + off;
    off = (off + bytes + 255) & ~(size_t)255;
    return q;
  };
  u16*   XP     = (u16*)  alloc((size_t)2 * T * NB * 512 * 2);  // 250 MiB
  u16*   Bt     = (u16*)  alloc((size_t)2 * 512 * KPAD * 2);
  float* Cproj  = (float*)alloc((size_t)2 * 4 * 512 * 4);
  float* rnn    = (float*)alloc((size_t)256 * 256 * 4);

  hipLaunchKernelGGL(prep_kernel, dim3(256), dim3(256), 0, stream,
                     cap_emb, Wfw, bfw, Wbw, bbw, Cproj, Bt);
  hipLaunchKernelGGL(xproj_kernel, dim3(1000, 4, 2), dim3(256), 0, stream,
                     words, caps, word_emb, Bt, Cproj, XP);
  hipLaunchKernelGGL(lstm_kernel, dim3(32), dim3(512), 0, stream,
                     XP, Wfw, Wbw, rnn);
  hipLaunchKernelGGL(head_kernel, dim3(256), dim3(64), 0, stream,
                     rnn, W1, b1, W2, b2, out);
}

// Round 8
// 696.065 us; speedup vs baseline: 1.0685x; 1.0066x over previous
//
#include <hip/hip_runtime.h>

#define T 500
#define NB 256
#define VROWS 50001
#define EMB 200
#define KPAD 224
#define MPAD 50048
#define LOG2E 1.44269504f

typedef unsigned short u16;
typedef __attribute__((ext_vector_type(8))) __bf16 bf16x8;
typedef __attribute__((ext_vector_type(8))) short short8;
typedef __attribute__((ext_vector_type(8))) u16 u16x8;
typedef __attribute__((ext_vector_type(4))) float f32x4;
typedef __attribute__((ext_vector_type(4))) u16 u16x4;

#define AS1 __attribute__((address_space(1)))
#define AS3 __attribute__((address_space(3)))

__device__ __forceinline__ u16 f2bf(float x) {
  __bf16 h = (__bf16)x;
  return __builtin_bit_cast(u16, h);
}
__device__ __forceinline__ float bf2f(u16 b) {
  union { unsigned u; float f; } v; v.u = ((unsigned)b) << 16;
  return v.f;
}
__device__ __forceinline__ float rcp_(float x) { return __builtin_amdgcn_rcpf(x); }
__device__ __forceinline__ float ex2_(float x) { return __builtin_amdgcn_exp2f(x); }
// gate scales: sig(x)=rcp(1+exp2(-LOG2E*x)); tanh(x)=1-2*rcp(1+exp2(2*LOG2E*x))
__device__ __forceinline__ float gsc(int g) { return (g == 1) ? 2.f * LOG2E : -LOG2E; }

// ---------------------------------------------------------------- prep ------
// Bt[dir][colp][KPAD] bf16 (pre-scaled Wx^T), Cproj[dir][cap][colp] f32,
// Apad[v][KPAD] bf16 word_emb (zero-padded) if apad != nullptr.
__global__ void prep_kernel(const float* __restrict__ cap_emb,
                            const float* __restrict__ word_emb,
                            const float* __restrict__ Wfw, const float* __restrict__ bfw,
                            const float* __restrict__ Wbw, const float* __restrict__ bbw,
                            float* __restrict__ Cproj, u16* __restrict__ Bt,
                            u16* __restrict__ Apad) {
  const int S2 = 2 * 512 * KPAD;
  const int S3 = 2 * 4 * 512;
  int tid = blockIdx.x * blockDim.x + threadIdx.x;
  int nthr = gridDim.x * blockDim.x;
  for (int i = tid; i < S2 + S3; i += nthr) {
    if (i < S2) {
      int d = i / (512 * KPAD), rem = i - d * (512 * KPAD);
      int colp = rem / KPAD, k = rem - colp * KPAD;
      const float* W = d ? Wbw : Wfw;
      int g = colp & 3, jj = colp >> 2;
      Bt[i] = (k < EMB) ? f2bf(W[k * 512 + g * 128 + jj] * gsc(g)) : (u16)0;
    } else {
      int idx = i - S2;
      int dir = idx >> 11; int c = (idx >> 9) & 3; int colp = idx & 511;
      int j = colp >> 2, g = colp & 3;
      const float* W = dir ? Wbw : Wfw;
      const float* bias = dir ? bbw : bfw;
      float v = bias[g * 128 + j] + (g == 2 ? 1.f : 0.f);   // fold forget_bias
      #pragma unroll
      for (int cc = 0; cc < 3; ++cc)
        v += cap_emb[c * 3 + cc] * W[(200 + cc) * 512 + g * 128 + j];
      Cproj[idx] = v * gsc(g);
    }
  }
  if (Apad) {
    const int S1 = MPAD * (KPAD / 4);
    for (int i = tid; i < S1; i += nthr) {
      int v = i / (KPAD / 4), q = i - v * (KPAD / 4);
      int k = q * 4;
      u16x4 o;
      if (v < VROWS && k < EMB) {
        const float* p = word_emb + (size_t)v * EMB + k;
        o[0] = f2bf(p[0]); o[1] = f2bf(p[1]); o[2] = f2bf(p[2]); o[3] = f2bf(p[3]);
      } else {
        o[0] = o[1] = o[2] = o[3] = 0;
      }
      *(u16x4*)(Apad + (size_t)v * KPAD + k) = o;
    }
  }
}

// ------------------------------------------------------------ XP GEMM -------
// XP[dir][t][b][colp] = bf16( emb(words[b][t]) @ Wx_scaled[:,colp]
//                             + Cproj[dir][caps[b][t]][colp] )
// Main path: A staged via global_load_lds gather from bf16 Apad;
// epilogue via f32 LDS transpose + coalesced u16x8 stores.
__global__ __launch_bounds__(256) void xproj_kernel(
    const int* __restrict__ words, const int* __restrict__ caps,
    const u16* __restrict__ Apad, const u16* __restrict__ Bt,
    const float* __restrict__ Cproj, u16* __restrict__ XP) {
  const int mt = blockIdx.x, nt = blockIdx.y, dir = blockIdx.z;
  const u16* __restrict__ B = Bt + (size_t)dir * 512 * KPAD;
  u16* __restrict__ xp = XP + (size_t)dir * T * NB * 512;

  __shared__ u16 As[2][128 * 32];
  __shared__ u16 Bs[2][128 * 32];
  __shared__ float Cls[64][132];     // col-major transpose buffer (one N-half)

  const int tid = threadIdx.x;
  const int w = tid >> 6, l = tid & 63;
  const int la = l & 15, lb = l >> 4;
  const int m0 = mt * 128, n0 = nt * 128;
  const int tblk = m0 >> 8;          // block-uniform timestep
  const int bbase = m0 & 255;

  // per-lane gather source bases for A staging (two 64-chunk halves)
  const int c0 = w * 128 + l, c1 = w * 128 + 64 + l;
  const int row0 = c0 >> 2, kq0 = c0 & 3;
  const int row1 = c1 >> 2, kq1 = c1 & 3;
  const int wd0 = words[(bbase + row0) * T + tblk];
  const int wd1 = words[(bbase + row1) * T + tblk];
  const u16* srcA0 = Apad + (size_t)wd0 * KPAD + kq0 * 8;
  const u16* srcA1 = Apad + (size_t)wd1 * KPAD + kq1 * 8;

  auto stage = [&](int buf, int ks) {
    __builtin_amdgcn_global_load_lds(
        (const AS1 void*)(srcA0 + ks * 32),
        (AS3 void*)&As[buf][(w * 128) * 8], 16, 0, 0);
    __builtin_amdgcn_global_load_lds(
        (const AS1 void*)(srcA1 + ks * 32),
        (AS3 void*)&As[buf][(w * 128 + 64) * 8], 16, 0, 0);
    int k0 = ks * 32;
    #pragma unroll
    for (int h = 0; h < 2; ++h) {
      int c = w * 128 + h * 64 + l;
      int row = c >> 2, kq = c & 3;
      const u16* gb = B + (size_t)(n0 + row) * KPAD + k0 + kq * 8;
      __builtin_amdgcn_global_load_lds(
          (const AS1 void*)gb,
          (AS3 void*)&Bs[buf][(w * 128 + h * 64) * 8], 16, 0, 0);
    }
  };

  f32x4 z = {0.f, 0.f, 0.f, 0.f};
  f32x4 acc[4][4] = {{z,z,z,z},{z,z,z,z},{z,z,z,z},{z,z,z,z}};
  const int wr = w >> 1, wc = w & 1;

  stage(0, 0);
  __syncthreads();
  #pragma unroll 1
  for (int ks = 0; ks < 7; ++ks) {
    int cur = ks & 1;
    if (ks < 6) stage(cur ^ 1, ks + 1);
    bf16x8 af[4], bfr[4];
    #pragma unroll
    for (int m = 0; m < 4; ++m)
      af[m] = *(const bf16x8*)&As[cur][(wr * 64 + m * 16 + la) * 32 + lb * 8];
    #pragma unroll
    for (int n = 0; n < 4; ++n)
      bfr[n] = *(const bf16x8*)&Bs[cur][(wc * 64 + n * 16 + la) * 32 + lb * 8];
    #pragma unroll
    for (int m = 0; m < 4; ++m)
      #pragma unroll
      for (int n = 0; n < 4; ++n)
        acc[m][n] = __builtin_amdgcn_mfma_f32_16x16x32_bf16(af[m], bfr[n], acc[m][n], 0, 0, 0);
    __syncthreads();
  }

  // epilogue: two N-half passes through Cls
  const int rrow = tid >> 1, rch = tid & 1;
  const int rb = bbase + rrow;
  const int rcap = caps[rb * T + tblk];
  const float* __restrict__ cbase = Cproj + (dir * 4 + rcap) * 512;
  u16* __restrict__ rop = xp + ((size_t)tblk * NB + rb) * 512;

  #pragma unroll
  for (int pass = 0; pass < 2; ++pass) {
    if (wc == pass) {
      #pragma unroll
      for (int m = 0; m < 4; ++m)
        #pragma unroll
        for (int n = 0; n < 4; ++n)
          *(f32x4*)&Cls[n * 16 + la][wr * 64 + m * 16 + lb * 4] = acc[m][n];
    }
    __syncthreads();
    int colp0 = n0 + pass * 64 + rch * 32;
    #pragma unroll
    for (int s = 0; s < 4; ++s) {
      u16x8 o;
      #pragma unroll
      for (int e = 0; e < 8; ++e) {
        int cl = rch * 32 + s * 8 + e;
        o[e] = f2bf(Cls[cl][rrow] + cbase[colp0 + s * 8 + e]);
      }
      *(u16x8*)(rop + colp0 + s * 8) = o;
    }
    __syncthreads();
  }
}

// Fallback (R7 path) when ws can't hold Apad: f32 scalar A-staging + scalar epilogue.
__global__ __launch_bounds__(256) void xproj_fb_kernel(
    const int* __restrict__ words, const int* __restrict__ caps,
    const float* __restrict__ word_emb, const u16* __restrict__ Bt,
    const float* __restrict__ Cproj, u16* __restrict__ XP) {
  const int mt = blockIdx.x, nt = blockIdx.y, dir = blockIdx.z;
  const u16* __restrict__ B = Bt + (size_t)dir * 512 * KPAD;
  const float* __restrict__ Cb = Cproj + dir * 4 * 512;
  u16* __restrict__ xp = XP + (size_t)dir * T * NB * 512;
  __shared__ u16 As[2][128 * 32];
  __shared__ u16 Bs[2][128 * 32];
  const int tid = threadIdx.x;
  const int w = tid >> 6, l = tid & 63;
  const int la = l & 15, lb = l >> 4;
  const int m0 = mt * 128, n0 = nt * 128;
  const int tblk = m0 >> 8;
  const int ar = tid >> 1, ah = tid & 1;
  const int ab = (m0 & 255) + ar;
  const int aword = words[ab * T + tblk];
  const float* __restrict__ aemb = word_emb + (size_t)aword * EMB;
  auto stageA = [&](int buf, int ks) {
    int kbase = ks * 32 + ah * 16;
    u16x8 lo, hi;
    #pragma unroll
    for (int q = 0; q < 4; ++q) {
      int k = kbase + q * 4;
      f32x4 v;
      if (k < EMB) v = *(const f32x4*)(aemb + k);
      else v = f32x4{0.f, 0.f, 0.f, 0.f};
      u16 b0 = f2bf(v[0]), b1 = f2bf(v[1]), b2 = f2bf(v[2]), b3 = f2bf(v[3]);
      if (q < 2) { lo[q*4+0]=b0; lo[q*4+1]=b1; lo[q*4+2]=b2; lo[q*4+3]=b3; }
      else { int qq=q-2; hi[qq*4+0]=b0; hi[qq*4+1]=b1; hi[qq*4+2]=b2; hi[qq*4+3]=b3; }
    }
    *(u16x8*)&As[buf][ar * 32 + ah * 16]     = lo;
    *(u16x8*)&As[buf][ar * 32 + ah * 16 + 8] = hi;
  };
  auto stageB = [&](int buf, int ks) {
    int k0 = ks * 32;
    #pragma unroll
    for (int h = 0; h < 2; ++h) {
      int c = w * 128 + h * 64 + l;
      int row = c >> 2, kq = c & 3;
      const u16* gb = B + (size_t)(n0 + row) * KPAD + k0 + kq * 8;
      __builtin_amdgcn_global_load_lds(
          (const AS1 void*)gb,
          (AS3 void*)&Bs[buf][(w * 128 + h * 64) * 8], 16, 0, 0);
    }
  };
  f32x4 z = {0.f, 0.f, 0.f, 0.f};
  f32x4 acc[4][4] = {{z,z,z,z},{z,z,z,z},{z,z,z,z},{z,z,z,z}};
  const int wr = w >> 1, wc = w & 1;
  stageA(0, 0); stageB(0, 0);
  __syncthreads();
  #pragma unroll 1
  for (int ks = 0; ks < 7; ++ks) {
    int cur = ks & 1;
    if (ks < 6) { stageA(cur ^ 1, ks + 1); stageB(cur ^ 1, ks + 1); }
    bf16x8 af[4], bfr[4];
    #pragma unroll
    for (int m = 0; m < 4; ++m)
      af[m] = *(const bf16x8*)&As[cur][(wr * 64 + m * 16 + la) * 32 + lb * 8];
    #pragma unroll
    for (int n = 0; n < 4; ++n)
      bfr[n] = *(const bf16x8*)&Bs[cur][(wc * 64 + n * 16 + la) * 32 + lb * 8];
    #pragma unroll
    for (int m = 0; m < 4; ++m)
      #pragma unroll
      for (int n = 0; n < 4; ++n)
        acc[m][n] = __builtin_amdgcn_mfma_f32_16x16x32_bf16(af[m], bfr[n], acc[m][n], 0, 0, 0);
    __syncthreads();
  }
  #pragma unroll
  for (int m = 0; m < 4; ++m) {
    #pragma unroll
    for (int r = 0; r < 4; ++r) {
      int b = (m0 & 255) + wr * 64 + m * 16 + lb * 4 + r;
      int cap = caps[b * T + tblk];
      const float* cbr = Cb + cap * 512;
      u16* op = xp + ((size_t)tblk * NB + b) * 512;
      #pragma unroll
      for (int n = 0; n < 4; ++n) {
        int colp = n0 + wc * 64 + n * 16 + la;
        op[colp] = f2bf(acc[m][n][r] + cbr[colp]);
      }
    }
  }
}

// ------------------------------------------------------------ LSTM ----------
// 8 waves (512 thr), 32 blocks (16 batch rows x 2 dir).
template <int PAR>
__device__ __forceinline__ void lstm_step(
    int t, int dir, int la, int lb, int j,
    const u16* __restrict__ xpd, int voff0, int voff1, int voff2, int voff3,
    const bf16x8 (&bfrag)[4][4], u16* __restrict__ hbuf,
    u16x4 (&xc)[4],            // data for t (consume)
    u16x4 (&xg)[4],            // load target for t+2
    f32x4& cst, f32x4& hl) {
  // A fragments (h_prev) from swizzled LDS
  const u16* hb = hbuf + PAR * 2048;
  const int swz = (la & 7) << 3;
  bf16x8 afr[4];
  #pragma unroll
  for (int kk = 0; kk < 4; ++kk)
    afr[kk] = *(const bf16x8*)(hb + ((la * 128 + kk * 32 + lb * 8) ^ swz));

  // issue xp loads for t+2 (linear stream, 2-step prefetch)
  {
    int ts = t + 2; if (ts > T - 1) ts = T - 1;
    int tt = dir ? (T - 1 - ts) : ts;
    const u16* p = xpd + (size_t)tt * (NB * 512);
    xg[0] = *(const u16x4*)(p + voff0);
    xg[1] = *(const u16x4*)(p + voff1);
    xg[2] = *(const u16x4*)(p + voff2);
    xg[3] = *(const u16x4*)(p + voff3);
  }

  // accumulators = x-projection (pre-scaled, bias+cap folded)
  f32x4 acc0, acc1, acc2, acc3;
  #pragma unroll
  for (int r = 0; r < 4; ++r) {
    acc0[r] = bf2f(xc[r][0]);
    acc1[r] = bf2f(xc[r][1]);
    acc2[r] = bf2f(xc[r][2]);
    acc3[r] = bf2f(xc[r][3]);
  }
  // gates += h_prev @ Wh (pre-scaled)
  __builtin_amdgcn_s_setprio(1);
  #pragma unroll
  for (int kk = 0; kk < 4; ++kk) {
    acc0 = __builtin_amdgcn_mfma_f32_16x16x32_bf16(afr[kk], bfrag[0][kk], acc0, 0, 0, 0);
    acc1 = __builtin_amdgcn_mfma_f32_16x16x32_bf16(afr[kk], bfrag[1][kk], acc1, 0, 0, 0);
    acc2 = __builtin_amdgcn_mfma_f32_16x16x32_bf16(afr[kk], bfrag[2][kk], acc2, 0, 0, 0);
    acc3 = __builtin_amdgcn_mfma_f32_16x16x32_bf16(afr[kk], bfrag[3][kk], acc3, 0, 0, 0);
  }
  __builtin_amdgcn_s_setprio(0);
  // cell update (8 trans/cell via fused reciprocals); write h_new (swizzled)
  u16* ho = hbuf + (PAR ^ 1) * 2048;
  #pragma unroll
  for (int r = 0; r < 4; ++r) {
    float ei = ex2_(acc0[r]);
    float ej = ex2_(acc1[r]);
    float ef = ex2_(acc2[r]);
    float eo = ex2_(acc3[r]);
    float itj = (ej - 1.f) * rcp_((1.f + ei) * (1.f + ej));
    float cn = cst[r] * rcp_(1.f + ef) + itj;
    cst[r] = cn;
    float E = ex2_(2.f * LOG2E * cn);
    float hn = (E - 1.f) * rcp_((1.f + eo) * (1.f + E));
    hl[r] = hn;
    int row = lb * 4 + r;
    ho[(row * 128 + j) ^ ((row & 7) << 3)] = f2bf(hn);
  }
  // LDS-only drain + raw barrier: vmcnt NOT drained, xp loads stay in flight
  __builtin_amdgcn_sched_barrier(0);
  asm volatile("s_waitcnt lgkmcnt(0)");
  __builtin_amdgcn_s_barrier();
  __builtin_amdgcn_sched_barrier(0);
}

__global__ __launch_bounds__(512, 1) void lstm_kernel(
    const u16* __restrict__ XP, const float* __restrict__ Wfw,
    const float* __restrict__ Wbw, float* __restrict__ rnn) {
  const int dir = blockIdx.x & 1;
  const int chunk = blockIdx.x >> 1;
  const int b0 = chunk * 16;
  const u16* __restrict__ xpd = XP + (size_t)dir * T * NB * 512;
  const float* __restrict__ W = dir ? Wbw : Wfw;

  const int tid = threadIdx.x;
  const int w = tid >> 6, l = tid & 63, la = l & 15, lb = l >> 4;
  const int j = w * 16 + la;

  const int voff0 = (b0 + lb * 4 + 0) * 512 + j * 4;
  const int voff1 = (b0 + lb * 4 + 1) * 512 + j * 4;
  const int voff2 = (b0 + lb * 4 + 2) * 512 + j * 4;
  const int voff3 = (b0 + lb * 4 + 3) * 512 + j * 4;

  // Wh fragments (pre-scaled): col = g*128 + j, k = kk*32 + lb*8 + r
  bf16x8 bfrag[4][4];
  #pragma unroll
  for (int g = 0; g < 4; ++g) {
    #pragma unroll
    for (int kk = 0; kk < 4; ++kk) {
      short8 t8;
      #pragma unroll
      for (int r = 0; r < 8; ++r) {
        int k = kk * 32 + lb * 8 + r;
        t8[r] = (short)f2bf(W[(203 + k) * 512 + g * 128 + j] * gsc(g));
      }
      bfrag[g][kk] = __builtin_bit_cast(bf16x8, t8);
    }
  }

  __shared__ u16 hbuf[2 * 16 * 128];
  for (int i = tid; i < 2 * 16 * 128; i += 512) hbuf[i] = 0;

  f32x4 cst = {0.f, 0.f, 0.f, 0.f};
  f32x4 hl  = {0.f, 0.f, 0.f, 0.f};

  u16x4 xA[4], xB[4], xC[4], xD[4];
  {
    int tt0 = dir ? (T - 1) : 0;
    int tt1 = dir ? (T - 2) : 1;
    const u16* p0 = xpd + (size_t)tt0 * (NB * 512);
    const u16* p1 = xpd + (size_t)tt1 * (NB * 512);
    xA[0] = *(const u16x4*)(p0 + voff0); xA[1] = *(const u16x4*)(p0 + voff1);
    xA[2] = *(const u16x4*)(p0 + voff2); xA[3] = *(const u16x4*)(p0 + voff3);
    xB[0] = *(const u16x4*)(p1 + voff0); xB[1] = *(const u16x4*)(p1 + voff1);
    xB[2] = *(const u16x4*)(p1 + voff2); xB[3] = *(const u16x4*)(p1 + voff3);
  }
  __syncthreads();

  #pragma unroll 1
  for (int tq = 0; tq < T / 4; ++tq) {
    int t0 = 4 * tq;
    lstm_step<0>(t0,     dir, la, lb, j, xpd, voff0, voff1, voff2, voff3,
                 bfrag, hbuf, xA, xC, cst, hl);
    lstm_step<1>(t0 + 1, dir, la, lb, j, xpd, voff0, voff1, voff2, voff3,
                 bfrag, hbuf, xB, xD, cst, hl);
    lstm_step<0>(t0 + 2, dir, la, lb, j, xpd, voff0, voff1, voff2, voff3,
                 bfrag, hbuf, xC, xA, cst, hl);
    lstm_step<1>(t0 + 3, dir, la, lb, j, xpd, voff0, voff1, voff2, voff3,
                 bfrag, hbuf, xD, xB, cst, hl);
  }

  #pragma unroll
  for (int r = 0; r < 4; ++r)
    rnn[(size_t)(b0 + lb * 4 + r) * 256 + dir * 128 + j] = hl[r];
}

// ------------------------------------------------------------ head ----------
__global__ void head_kernel(const float* __restrict__ rnn, const float* __restrict__ W1,
                            const float* __restrict__ b1, const float* __restrict__ W2,
                            const float* __restrict__ b2, float* __restrict__ out) {
  int b = blockIdx.x;
  int jj = threadIdx.x;  // 64 threads
  __shared__ float d1[64];
  float acc = b1[jj];
  const float* r = rnn + b * 256;
  #pragma unroll 4
  for (int k = 0; k < 256; ++k) acc += r[k] * W1[k * 64 + jj];
  d1[jj] = acc > 0.f ? acc : (__expf(acc) - 1.f);
  __syncthreads();
  if (jj < 6) {
    float a2 = b2[jj];
    #pragma unroll 8
    for (int k = 0; k < 64; ++k) a2 += d1[k] * W2[k * 6 + jj];
    out[b * 6 + jj] = rcp_(1.f + __expf(-a2));
  }
}

// ------------------------------------------------------------ launch --------
extern "C" void kernel_launch(void* const* d_in, const int* in_sizes, int n_in,
                              void* d_out, int out_size, void* d_ws, size_t ws_size,
                              hipStream_t stream) {
  (void)in_sizes; (void)n_in; (void)out_size;
  const int*   words    = (const int*)  d_in[0];
  const int*   caps     = (const int*)  d_in[1];
  const float* word_emb = (const float*)d_in[2];
  const float* cap_emb  = (const float*)d_in[3];
  const float* Wfw      = (const float*)d_in[4];
  const float* bfw      = (const float*)d_in[5];
  const float* Wbw      = (const float*)d_in[6];
  const float* bbw      = (const float*)d_in[7];
  const float* W1       = (const float*)d_in[8];
  const float* b1       = (const float*)d_in[9];
  const float* W2       = (const float*)d_in[10];
  const float* b2       = (const float*)d_in[11];
  float* out = (float*)d_out;

  char* base = (char*)d_ws;
  size_t off = 0;
  auto alloc = [&](size_t bytes) {
    char* q = base + off;
    off = (off + bytes + 255) & ~(size_t)255;
    return q;
  };
  u16*   XP     = (u16*)  alloc((size_t)2 * T * NB * 512 * 2);   // 262 MB
  u16*   Bt     = (u16*)  alloc((size_t)2 * 512 * KPAD * 2);
  float* Cproj  = (float*)alloc((size_t)2 * 4 * 512 * 4);
  float* rnn    = (float*)alloc((size_t)256 * 256 * 4);
  size_t off_no_apad = off;
  u16*   Apad   = (u16*)  alloc((size_t)MPAD * KPAD * 2);        // +22.4 MB
  bool use_apad = (off <= ws_size);
  if (!use_apad) { Apad = nullptr; off = off_no_apad; }

  hipLaunchKernelGGL(prep_kernel, dim3(2048), dim3(256), 0, stream,
                     cap_emb, word_emb, Wfw, bfw, Wbw, bbw, Cproj, Bt, Apad);
  if (use_apad) {
    hipLaunchKernelGGL(xproj_kernel, dim3(1000, 4, 2), dim3(256), 0, stream,
                       words, caps, Apad, Bt, Cproj, XP);
  } else {
    hipLaunchKernelGGL(xproj_fb_kernel, dim3(1000, 4, 2), dim3(256), 0, stream,
                       words, caps, word_emb, Bt, Cproj, XP);
  }
  hipLaunchKernelGGL(lstm_kernel, dim3(32), dim3(512), 0, stream,
                     XP, Wfw, Wbw, rnn);
  hipLaunchKernelGGL(head_kernel, dim3(256), dim3(64), 0, stream,
                     rnn, W1, b1, W2, b2, out);
}

// Round 10
// 668.550 us; speedup vs baseline: 1.1125x; 1.0412x over previous
//
#include <hip/hip_runtime.h>

#define T 500
#define NB 256
#define VROWS 50001
#define EMB 200
#define KPAD 224
#define LOG2E 1.44269504f

typedef unsigned short u16;
typedef __attribute__((ext_vector_type(8))) __bf16 bf16x8;
typedef __attribute__((ext_vector_type(8))) short short8;
typedef __attribute__((ext_vector_type(8))) u16 u16x8;
typedef __attribute__((ext_vector_type(4))) float f32x4;
typedef __attribute__((ext_vector_type(4))) u16 u16x4;

#define AS1 __attribute__((address_space(1)))
#define AS3 __attribute__((address_space(3)))

__device__ __forceinline__ u16 f2bf(float x) {
  __bf16 h = (__bf16)x;
  return __builtin_bit_cast(u16, h);
}
__device__ __forceinline__ float bf2f(u16 b) {
  union { unsigned u; float f; } v; v.u = ((unsigned)b) << 16;
  return v.f;
}
__device__ __forceinline__ float rcp_(float x) { return __builtin_amdgcn_rcpf(x); }
__device__ __forceinline__ float ex2_(float x) { return __builtin_amdgcn_exp2f(x); }
// gate scales: sig(x)=rcp(1+exp2(-LOG2E*x)); tanh(x)=1-2*rcp(1+exp2(2*LOG2E*x))
__device__ __forceinline__ float gsc(int g) { return (g == 1) ? 2.f * LOG2E : -LOG2E; }

// ---------------------------------------------------------------- prep ------
// Bt[dir][colp][KPAD] bf16 (pre-scaled Wx^T, zero rows for k>=EMB),
// Cproj[dir][cap][colp] f32 (pre-scaled bias + forget_bias + cap one-hot).
__global__ void prep_kernel(const float* __restrict__ cap_emb,
                            const float* __restrict__ Wfw, const float* __restrict__ bfw,
                            const float* __restrict__ Wbw, const float* __restrict__ bbw,
                            float* __restrict__ Cproj, u16* __restrict__ Bt) {
  const int S2 = 2 * 512 * KPAD;
  const int S3 = 2 * 4 * 512;
  int tid = blockIdx.x * blockDim.x + threadIdx.x;
  int nthr = gridDim.x * blockDim.x;
  for (int i = tid; i < S2 + S3; i += nthr) {
    if (i < S2) {
      int d = i / (512 * KPAD), rem = i - d * (512 * KPAD);
      int colp = rem / KPAD, k = rem - colp * KPAD;
      const float* W = d ? Wbw : Wfw;
      int g = colp & 3, jj = colp >> 2;
      Bt[i] = (k < EMB) ? f2bf(W[k * 512 + g * 128 + jj] * gsc(g)) : (u16)0;
    } else {
      int idx = i - S2;
      int dir = idx >> 11; int c = (idx >> 9) & 3; int colp = idx & 511;
      int j = colp >> 2, g = colp & 3;
      const float* W = dir ? Wbw : Wfw;
      const float* bias = dir ? bbw : bfw;
      float v = bias[g * 128 + j] + (g == 2 ? 1.f : 0.f);   // fold forget_bias
      #pragma unroll
      for (int cc = 0; cc < 3; ++cc)
        v += cap_emb[c * 3 + cc] * W[(200 + cc) * 512 + g * 128 + j];
      Cproj[idx] = v * gsc(g);
    }
  }
}

// ------------------------------------------------------------ XP GEMM -------
// XP[dir][t][b][colp] = bf16( emb(words[b][t]) @ Wx_scaled[:,colp]
//                             + Cproj[dir][caps[b][t]][colp] )
// A reg-staged from f32 word_emb (1 k-step ahead); B via global_load_lds with
// pre-swizzled SOURCE (linear LDS dest); swizzled frag reads; plain
// __syncthreads() double-buffer (no inline asm — R9's counted-vmcnt raced).
__global__ __launch_bounds__(256) void xproj_kernel(
    const int* __restrict__ words, const int* __restrict__ caps,
    const float* __restrict__ word_emb, const u16* __restrict__ Bt,
    const float* __restrict__ Cproj, u16* __restrict__ XP) {
  const int mt = blockIdx.x, nt = blockIdx.y, dir = blockIdx.z;
  const u16* __restrict__ B = Bt + (size_t)dir * 512 * KPAD;
  u16* __restrict__ xp = XP + (size_t)dir * T * NB * 512;

  __shared__ __align__(16) char pool[34048];
  u16* As = (u16*)pool;                 // [2][4096] u16  (16 KB)
  u16* Bs = (u16*)(pool + 16384);       // [2][4096] u16  (16 KB)
  float (*Cls)[132] = (float(*)[132])pool;  // epilogue alias (33.8 KB)

  const int tid = threadIdx.x;
  const int w = tid >> 6, l = tid & 63;
  const int la = l & 15, lb = l >> 4;
  const int wr = w >> 1, wc = w & 1;
  const int tblk = mt >> 1;
  const int bbase = (mt & 1) * 128;
  const int n0 = nt * 128;

  // ---- A staging: thread -> row tid>>1, k-half tid&1 (16 k each) ----
  const int arow = tid >> 1, khalf = tid & 1;
  const int wd = words[(bbase + arow) * T + tblk];
  const float* __restrict__ aemb = word_emb + (size_t)wd * EMB;
  // swizzled u16 dest indices for the two 16B chunks (chunk c at pos c^(row&3))
  const int aswz0 = (arow * 4 + ((khalf * 2 + 0) ^ (arow & 3))) * 8;
  const int aswz1 = (arow * 4 + ((khalf * 2 + 1) ^ (arow & 3))) * 8;

  // ---- B staging: per-lane pre-swizzled source, linear LDS dest ----
  // slot s (= lane-order dest) holds source chunk (rn = s>>2, c = (s&3)^(rn&3))
  const int s0 = w * 128 + l, s1 = w * 128 + 64 + l;
  const int brn0 = s0 >> 2, bc0 = (s0 & 3) ^ (brn0 & 3);
  const int brn1 = s1 >> 2, bc1 = (s1 & 3) ^ (brn1 & 3);
  const u16* bsrc0 = B + (size_t)(n0 + brn0) * KPAD + bc0 * 8;
  const u16* bsrc1 = B + (size_t)(n0 + brn1) * KPAD + bc1 * 8;

  f32x4 va[4];
  auto loadA = [&](int ks) {
    #pragma unroll
    for (int q = 0; q < 4; ++q)
      va[q] = *(const f32x4*)(aemb + ks * 32 + khalf * 16 + q * 4);
    // k beyond EMB reads into the next table row (in-bounds; max offset 224
    // from row<=49999 of a 50001-row table): finite garbage that multiplies
    // Bt's zero rows (k>=EMB) -> contributes exactly 0.
  };
  auto writeA = [&](int buf) {
    u16x8 lo, hi;
    #pragma unroll
    for (int e = 0; e < 4; ++e) {
      lo[e] = f2bf(va[0][e]); lo[4 + e] = f2bf(va[1][e]);
      hi[e] = f2bf(va[2][e]); hi[4 + e] = f2bf(va[3][e]);
    }
    *(u16x8*)&As[buf * 4096 + aswz0] = lo;
    *(u16x8*)&As[buf * 4096 + aswz1] = hi;
  };
  auto stageB = [&](int buf, int ks) {
    __builtin_amdgcn_global_load_lds(
        (const AS1 void*)(bsrc0 + ks * 32),
        (AS3 void*)&Bs[buf * 4096 + (w * 128) * 8], 16, 0, 0);
    __builtin_amdgcn_global_load_lds(
        (const AS1 void*)(bsrc1 + ks * 32),
        (AS3 void*)&Bs[buf * 4096 + (w * 128 + 64) * 8], 16, 0, 0);
  };

  f32x4 z = {0.f, 0.f, 0.f, 0.f};
  f32x4 acc[4][4] = {{z,z,z,z},{z,z,z,z},{z,z,z,z},{z,z,z,z}};

  // prologue: stage k-step 0 into buffer 0
  loadA(0);
  stageB(0, 0);
  writeA(0);
  __syncthreads();

  #pragma unroll 1
  for (int ks = 0; ks < 7; ++ks) {
    const int cur = ks & 1;
    if (ks < 6) { stageB(cur ^ 1, ks + 1); loadA(ks + 1); }
    bf16x8 af[4], bfr[4];
    #pragma unroll
    for (int m = 0; m < 4; ++m) {
      int ra = wr * 64 + m * 16 + la;
      af[m] = *(const bf16x8*)&As[cur * 4096 + ra * 32 + ((lb ^ (ra & 3)) * 8)];
    }
    #pragma unroll
    for (int n = 0; n < 4; ++n) {
      int rn = wc * 64 + n * 16 + la;
      bfr[n] = *(const bf16x8*)&Bs[cur * 4096 + rn * 32 + ((lb ^ (rn & 3)) * 8)];
    }
    #pragma unroll
    for (int m = 0; m < 4; ++m)
      #pragma unroll
      for (int n = 0; n < 4; ++n)
        acc[m][n] = __builtin_amdgcn_mfma_f32_16x16x32_bf16(af[m], bfr[n], acc[m][n], 0, 0, 0);
    if (ks < 6) writeA(cur ^ 1);
    __syncthreads();   // full drain (vmcnt+lgkm) — safe; TLP across 4 blocks/CU hides it
  }

  // epilogue: two N-half passes through the aliased transpose buffer
  const int rrow = tid >> 1, rch = tid & 1;
  const int rb = bbase + rrow;
  const int rcap = caps[rb * T + tblk];
  const float* __restrict__ cbase = Cproj + (dir * 4 + rcap) * 512;
  u16* __restrict__ rop = xp + ((size_t)tblk * NB + rb) * 512;

  #pragma unroll
  for (int pass = 0; pass < 2; ++pass) {
    if (wc == pass) {
      #pragma unroll
      for (int m = 0; m < 4; ++m)
        #pragma unroll
        for (int n = 0; n < 4; ++n)
          *(f32x4*)&Cls[n * 16 + la][wr * 64 + m * 16 + lb * 4] = acc[m][n];
    }
    __syncthreads();
    int colp0 = n0 + pass * 64 + rch * 32;
    #pragma unroll
    for (int s = 0; s < 4; ++s) {
      u16x8 o;
      #pragma unroll
      for (int e = 0; e < 8; ++e) {
        int cl = rch * 32 + s * 8 + e;
        o[e] = f2bf(Cls[cl][rrow] + cbase[colp0 + s * 8 + e]);
      }
      *(u16x8*)(rop + colp0 + s * 8) = o;
    }
    __syncthreads();
  }
}

// ------------------------------------------------------------ LSTM ----------
// 8 waves (512 thr), 32 blocks (16 batch rows x 2 dir).  Unchanged from R8.
template <int PAR>
__device__ __forceinline__ void lstm_step(
    int t, int dir, int la, int lb, int j,
    const u16* __restrict__ xpd, int voff0, int voff1, int voff2, int voff3,
    const bf16x8 (&bfrag)[4][4], u16* __restrict__ hbuf,
    u16x4 (&xc)[4],            // data for t (consume)
    u16x4 (&xg)[4],            // load target for t+2
    f32x4& cst, f32x4& hl) {
  // A fragments (h_prev) from swizzled LDS
  const u16* hb = hbuf + PAR * 2048;
  const int swz = (la & 7) << 3;
  bf16x8 afr[4];
  #pragma unroll
  for (int kk = 0; kk < 4; ++kk)
    afr[kk] = *(const bf16x8*)(hb + ((la * 128 + kk * 32 + lb * 8) ^ swz));

  // issue xp loads for t+2 (linear stream, 2-step prefetch)
  {
    int ts = t + 2; if (ts > T - 1) ts = T - 1;
    int tt = dir ? (T - 1 - ts) : ts;
    const u16* p = xpd + (size_t)tt * (NB * 512);
    xg[0] = *(const u16x4*)(p + voff0);
    xg[1] = *(const u16x4*)(p + voff1);
    xg[2] = *(const u16x4*)(p + voff2);
    xg[3] = *(const u16x4*)(p + voff3);
  }

  // accumulators = x-projection (pre-scaled, bias+cap folded)
  f32x4 acc0, acc1, acc2, acc3;
  #pragma unroll
  for (int r = 0; r < 4; ++r) {
    acc0[r] = bf2f(xc[r][0]);
    acc1[r] = bf2f(xc[r][1]);
    acc2[r] = bf2f(xc[r][2]);
    acc3[r] = bf2f(xc[r][3]);
  }
  // gates += h_prev @ Wh (pre-scaled)
  __builtin_amdgcn_s_setprio(1);
  #pragma unroll
  for (int kk = 0; kk < 4; ++kk) {
    acc0 = __builtin_amdgcn_mfma_f32_16x16x32_bf16(afr[kk], bfrag[0][kk], acc0, 0, 0, 0);
    acc1 = __builtin_amdgcn_mfma_f32_16x16x32_bf16(afr[kk], bfrag[1][kk], acc1, 0, 0, 0);
    acc2 = __builtin_amdgcn_mfma_f32_16x16x32_bf16(afr[kk], bfrag[2][kk], acc2, 0, 0, 0);
    acc3 = __builtin_amdgcn_mfma_f32_16x16x32_bf16(afr[kk], bfrag[3][kk], acc3, 0, 0, 0);
  }
  __builtin_amdgcn_s_setprio(0);
  // cell update (fused reciprocals); write h_new to other buffer (swizzled)
  u16* ho = hbuf + (PAR ^ 1) * 2048;
  #pragma unroll
  for (int r = 0; r < 4; ++r) {
    float ei = ex2_(acc0[r]);
    float ej = ex2_(acc1[r]);
    float ef = ex2_(acc2[r]);
    float eo = ex2_(acc3[r]);
    float itj = (ej - 1.f) * rcp_((1.f + ei) * (1.f + ej));
    float cn = cst[r] * rcp_(1.f + ef) + itj;
    cst[r] = cn;
    float E = ex2_(2.f * LOG2E * cn);
    float hn = (E - 1.f) * rcp_((1.f + eo) * (1.f + E));
    hl[r] = hn;
    int row = lb * 4 + r;
    ho[(row * 128 + j) ^ ((row & 7) << 3)] = f2bf(hn);
  }
  // LDS-only drain + raw barrier: vmcnt NOT drained, xp loads stay in flight
  __builtin_amdgcn_sched_barrier(0);
  asm volatile("s_waitcnt lgkmcnt(0)");
  __builtin_amdgcn_s_barrier();
  __builtin_amdgcn_sched_barrier(0);
}

__global__ __launch_bounds__(512, 1) void lstm_kernel(
    const u16* __restrict__ XP, const float* __restrict__ Wfw,
    const float* __restrict__ Wbw, float* __restrict__ rnn) {
  const int dir = blockIdx.x & 1;
  const int chunk = blockIdx.x >> 1;
  const int b0 = chunk * 16;
  const u16* __restrict__ xpd = XP + (size_t)dir * T * NB * 512;
  const float* __restrict__ W = dir ? Wbw : Wfw;

  const int tid = threadIdx.x;
  const int w = tid >> 6, l = tid & 63, la = l & 15, lb = l >> 4;
  const int j = w * 16 + la;

  const int voff0 = (b0 + lb * 4 + 0) * 512 + j * 4;
  const int voff1 = (b0 + lb * 4 + 1) * 512 + j * 4;
  const int voff2 = (b0 + lb * 4 + 2) * 512 + j * 4;
  const int voff3 = (b0 + lb * 4 + 3) * 512 + j * 4;

  // Wh fragments (pre-scaled): col = g*128 + j, k = kk*32 + lb*8 + r
  bf16x8 bfrag[4][4];
  #pragma unroll
  for (int g = 0; g < 4; ++g) {
    #pragma unroll
    for (int kk = 0; kk < 4; ++kk) {
      short8 t8;
      #pragma unroll
      for (int r = 0; r < 8; ++r) {
        int k = kk * 32 + lb * 8 + r;
        t8[r] = (short)f2bf(W[(203 + k) * 512 + g * 128 + j] * gsc(g));
      }
      bfrag[g][kk] = __builtin_bit_cast(bf16x8, t8);
    }
  }

  __shared__ u16 hbuf[2 * 16 * 128];
  for (int i = tid; i < 2 * 16 * 128; i += 512) hbuf[i] = 0;

  f32x4 cst = {0.f, 0.f, 0.f, 0.f};
  f32x4 hl  = {0.f, 0.f, 0.f, 0.f};

  u16x4 xA[4], xB[4], xC[4], xD[4];
  {
    int tt0 = dir ? (T - 1) : 0;
    int tt1 = dir ? (T - 2) : 1;
    const u16* p0 = xpd + (size_t)tt0 * (NB * 512);
    const u16* p1 = xpd + (size_t)tt1 * (NB * 512);
    xA[0] = *(const u16x4*)(p0 + voff0); xA[1] = *(const u16x4*)(p0 + voff1);
    xA[2] = *(const u16x4*)(p0 + voff2); xA[3] = *(const u16x4*)(p0 + voff3);
    xB[0] = *(const u16x4*)(p1 + voff0); xB[1] = *(const u16x4*)(p1 + voff1);
    xB[2] = *(const u16x4*)(p1 + voff2); xB[3] = *(const u16x4*)(p1 + voff3);
  }
  __syncthreads();

  #pragma unroll 1
  for (int tq = 0; tq < T / 4; ++tq) {
    int t0 = 4 * tq;
    lstm_step<0>(t0,     dir, la, lb, j, xpd, voff0, voff1, voff2, voff3,
                 bfrag, hbuf, xA, xC, cst, hl);
    lstm_step<1>(t0 + 1, dir, la, lb, j, xpd, voff0, voff1, voff2, voff3,
                 bfrag, hbuf, xB, xD, cst, hl);
    lstm_step<0>(t0 + 2, dir, la, lb, j, xpd, voff0, voff1, voff2, voff3,
                 bfrag, hbuf, xC, xA, cst, hl);
    lstm_step<1>(t0 + 3, dir, la, lb, j, xpd, voff0, voff1, voff2, voff3,
                 bfrag, hbuf, xD, xB, cst, hl);
  }

  #pragma unroll
  for (int r = 0; r < 4; ++r)
    rnn[(size_t)(b0 + lb * 4 + r) * 256 + dir * 128 + j] = hl[r];
}

// ------------------------------------------------------------ head ----------
__global__ void head_kernel(const float* __restrict__ rnn, const float* __restrict__ W1,
                            const float* __restrict__ b1, const float* __restrict__ W2,
                            const float* __restrict__ b2, float* __restrict__ out) {
  int b = blockIdx.x;
  int jj = threadIdx.x;  // 64 threads
  __shared__ float d1[64];
  float acc = b1[jj];
  const float* r = rnn + b * 256;
  #pragma unroll 4
  for (int k = 0; k < 256; ++k) acc += r[k] * W1[k * 64 + jj];
  d1[jj] = acc > 0.f ? acc : (__expf(acc) - 1.f);
  __syncthreads();
  if (jj < 6) {
    float a2 = b2[jj];
    #pragma unroll 8
    for (int k = 0; k < 64; ++k) a2 += d1[k] * W2[k * 6 + jj];
    out[b * 6 + jj] = rcp_(1.f + __expf(-a2));
  }
}

// ------------------------------------------------------------ launch --------
extern "C" void kernel_launch(void* const* d_in, const int* in_sizes, int n_in,
                              void* d_out, int out_size, void* d_ws, size_t ws_size,
                              hipStream_t stream) {
  (void)in_sizes; (void)n_in; (void)out_size; (void)ws_size;
  const int*   words    = (const int*)  d_in[0];
  const int*   caps     = (const int*)  d_in[1];
  const float* word_emb = (const float*)d_in[2];
  const float* cap_emb  = (const float*)d_in[3];
  const float* Wfw      = (const float*)d_in[4];
  const float* bfw      = (const float*)d_in[5];
  const float* Wbw      = (const float*)d_in[6];
  const float* bbw      = (const float*)d_in[7];
  const float* W1       = (const float*)d_in[8];
  const float* b1       = (const float*)d_in[9];
  const float* W2       = (const float*)d_in[10];
  const float* b2       = (const float*)d_in[11];
  float* out = (float*)d_out;

  char* base = (char*)d_ws;
  size_t off = 0;
  auto alloc = [&](size_t bytes) {
    char* q = base + off;
    off = (off + bytes + 255) & ~(size_t)255;
    return q;
  };
  u16*   XP     = (u16*)  alloc((size_t)2 * T * NB * 512 * 2);   // 262.1 MB
  u16*   Bt     = (u16*)  alloc((size_t)2 * 512 * KPAD * 2);
  float* Cproj  = (float*)alloc((size_t)2 * 4 * 512 * 4);
  float* rnn    = (float*)alloc((size_t)256 * 256 * 4);
  // total ~262.9 MB == R7-proven budget.

  hipLaunchKernelGGL(prep_kernel, dim3(256), dim3(256), 0, stream,
                     cap_emb, Wfw, bfw, Wbw, bbw, Cproj, Bt);
  hipLaunchKernelGGL(xproj_kernel, dim3(1000, 4, 2), dim3(256), 0, stream,
                     words, caps, word_emb, Bt, Cproj, XP);
  hipLaunchKernelGGL(lstm_kernel, dim3(32), dim3(512), 0, stream,
                     XP, Wfw, Wbw, rnn);
  hipLaunchKernelGGL(head_kernel, dim3(256), dim3(64), 0, stream,
                     rnn, W1, b1, W2, b2, out);
}

// Round 11
// 627.252 us; speedup vs baseline: 1.1857x; 1.0658x over previous
//
#include <hip/hip_runtime.h>

#define T 500
#define NB 256
#define VROWS 50001
#define EMB 200
#define KPAD 224
#define LOG2E 1.44269504f

typedef unsigned short u16;
typedef __attribute__((ext_vector_type(8))) __bf16 bf16x8;
typedef __attribute__((ext_vector_type(8))) short short8;
typedef __attribute__((ext_vector_type(8))) u16 u16x8;
typedef __attribute__((ext_vector_type(4))) float f32x4;
typedef __attribute__((ext_vector_type(4))) u16 u16x4;

#define AS1 __attribute__((address_space(1)))
#define AS3 __attribute__((address_space(3)))

__device__ __forceinline__ u16 f2bf(float x) {
  __bf16 h = (__bf16)x;
  return __builtin_bit_cast(u16, h);
}
__device__ __forceinline__ float bf2f(u16 b) {
  union { unsigned u; float f; } v; v.u = ((unsigned)b) << 16;
  return v.f;
}
__device__ __forceinline__ float rcp_(float x) { return __builtin_amdgcn_rcpf(x); }
__device__ __forceinline__ float ex2_(float x) { return __builtin_amdgcn_exp2f(x); }
// gate scales: sig(x)=rcp(1+exp2(-LOG2E*x)); tanh(x)=1-2*rcp(1+exp2(2*LOG2E*x))
__device__ __forceinline__ float gsc(int g) { return (g == 1) ? 2.f * LOG2E : -LOG2E; }

// ---------------------------------------------------------------- prep ------
// Bt[dir][colp][KPAD] bf16 (pre-scaled Wx^T, zero rows for k>=EMB),
// Cproj[dir][cap][colp] f32 (pre-scaled bias + forget_bias + cap one-hot).
__global__ void prep_kernel(const float* __restrict__ cap_emb,
                            const float* __restrict__ Wfw, const float* __restrict__ bfw,
                            const float* __restrict__ Wbw, const float* __restrict__ bbw,
                            float* __restrict__ Cproj, u16* __restrict__ Bt) {
  const int S2 = 2 * 512 * KPAD;
  const int S3 = 2 * 4 * 512;
  int tid = blockIdx.x * blockDim.x + threadIdx.x;
  int nthr = gridDim.x * blockDim.x;
  for (int i = tid; i < S2 + S3; i += nthr) {
    if (i < S2) {
      int d = i / (512 * KPAD), rem = i - d * (512 * KPAD);
      int colp = rem / KPAD, k = rem - colp * KPAD;
      const float* W = d ? Wbw : Wfw;
      int g = colp & 3, jj = colp >> 2;
      Bt[i] = (k < EMB) ? f2bf(W[k * 512 + g * 128 + jj] * gsc(g)) : (u16)0;
    } else {
      int idx = i - S2;
      int dir = idx >> 11; int c = (idx >> 9) & 3; int colp = idx & 511;
      int j = colp >> 2, g = colp & 3;
      const float* W = dir ? Wbw : Wfw;
      const float* bias = dir ? bbw : bfw;
      float v = bias[g * 128 + j] + (g == 2 ? 1.f : 0.f);   // fold forget_bias
      #pragma unroll
      for (int cc = 0; cc < 3; ++cc)
        v += cap_emb[c * 3 + cc] * W[(200 + cc) * 512 + g * 128 + j];
      Cproj[idx] = v * gsc(g);
    }
  }
}

// ------------------------------------------------------------ XP GEMM -------
// XP[dir][t][b][colp] = bf16( emb(words[b][t]) @ Wx_scaled[:,colp]
//                             + Cproj[dir][caps[b][t]][colp] )
// 1D grid of 8000 with XCD-grouping swizzle: the 8 blocks (4 nt x 2 dir)
// sharing one A-tile (same mt) get xcd = mt%8 and consecutive slots ->
// co-resident on one XCD -> A read from L3 once, then L2-hits (8x less
// gathered A traffic).  A reg-staged from f32 word_emb; B via global_load_lds
// with pre-swizzled source; plain __syncthreads() double-buffer.
__global__ __launch_bounds__(256) void xproj_kernel(
    const int* __restrict__ words, const int* __restrict__ caps,
    const float* __restrict__ word_emb, const u16* __restrict__ Bt,
    const float* __restrict__ Cproj, u16* __restrict__ XP) {
  // decode swizzled block id: bid = ((mt/8)*8 + nt + 4*dir)*8 + mt%8
  const int bid = blockIdx.x;
  const int xcd = bid & 7, slot = bid >> 3;
  const int mt = (slot >> 3) * 8 + xcd;
  const int inner = slot & 7;
  const int nt = inner & 3, dir = inner >> 2;

  const u16* __restrict__ B = Bt + (size_t)dir * 512 * KPAD;
  u16* __restrict__ xp = XP + (size_t)dir * T * NB * 512;

  __shared__ __align__(16) char pool[34048];
  u16* As = (u16*)pool;                 // [2][4096] u16  (16 KB)
  u16* Bs = (u16*)(pool + 16384);       // [2][4096] u16  (16 KB)
  float (*Cls)[132] = (float(*)[132])pool;  // epilogue alias (33.8 KB)

  const int tid = threadIdx.x;
  const int w = tid >> 6, l = tid & 63;
  const int la = l & 15, lb = l >> 4;
  const int wr = w >> 1, wc = w & 1;
  const int tblk = mt >> 1;
  const int bbase = (mt & 1) * 128;
  const int n0 = nt * 128;

  // ---- A staging: thread -> row tid>>1, k-half tid&1 (16 k each) ----
  const int arow = tid >> 1, khalf = tid & 1;
  const int wd = words[(bbase + arow) * T + tblk];
  const float* __restrict__ aemb = word_emb + (size_t)wd * EMB;
  // swizzled u16 dest indices for the two 16B chunks (chunk c at pos c^(row&3))
  const int aswz0 = (arow * 4 + ((khalf * 2 + 0) ^ (arow & 3))) * 8;
  const int aswz1 = (arow * 4 + ((khalf * 2 + 1) ^ (arow & 3))) * 8;

  // ---- B staging: per-lane pre-swizzled source, linear LDS dest ----
  const int s0 = w * 128 + l, s1 = w * 128 + 64 + l;
  const int brn0 = s0 >> 2, bc0 = (s0 & 3) ^ (brn0 & 3);
  const int brn1 = s1 >> 2, bc1 = (s1 & 3) ^ (brn1 & 3);
  const u16* bsrc0 = B + (size_t)(n0 + brn0) * KPAD + bc0 * 8;
  const u16* bsrc1 = B + (size_t)(n0 + brn1) * KPAD + bc1 * 8;

  f32x4 va[4];
  auto loadA = [&](int ks) {
    #pragma unroll
    for (int q = 0; q < 4; ++q)
      va[q] = *(const f32x4*)(aemb + ks * 32 + khalf * 16 + q * 4);
    // k beyond EMB reads the next table row (in-bounds): finite garbage that
    // multiplies Bt's zero rows (k>=EMB) -> contributes exactly 0.
  };
  auto writeA = [&](int buf) {
    u16x8 lo, hi;
    #pragma unroll
    for (int e = 0; e < 4; ++e) {
      lo[e] = f2bf(va[0][e]); lo[4 + e] = f2bf(va[1][e]);
      hi[e] = f2bf(va[2][e]); hi[4 + e] = f2bf(va[3][e]);
    }
    *(u16x8*)&As[buf * 4096 + aswz0] = lo;
    *(u16x8*)&As[buf * 4096 + aswz1] = hi;
  };
  auto stageB = [&](int buf, int ks) {
    __builtin_amdgcn_global_load_lds(
        (const AS1 void*)(bsrc0 + ks * 32),
        (AS3 void*)&Bs[buf * 4096 + (w * 128) * 8], 16, 0, 0);
    __builtin_amdgcn_global_load_lds(
        (const AS1 void*)(bsrc1 + ks * 32),
        (AS3 void*)&Bs[buf * 4096 + (w * 128 + 64) * 8], 16, 0, 0);
  };

  f32x4 z = {0.f, 0.f, 0.f, 0.f};
  f32x4 acc[4][4] = {{z,z,z,z},{z,z,z,z},{z,z,z,z},{z,z,z,z}};

  // prologue: stage k-step 0 into buffer 0
  loadA(0);
  stageB(0, 0);
  writeA(0);
  __syncthreads();

  #pragma unroll 1
  for (int ks = 0; ks < 7; ++ks) {
    const int cur = ks & 1;
    if (ks < 6) { stageB(cur ^ 1, ks + 1); loadA(ks + 1); }
    bf16x8 af[4], bfr[4];
    #pragma unroll
    for (int m = 0; m < 4; ++m) {
      int ra = wr * 64 + m * 16 + la;
      af[m] = *(const bf16x8*)&As[cur * 4096 + ra * 32 + ((lb ^ (ra & 3)) * 8)];
    }
    #pragma unroll
    for (int n = 0; n < 4; ++n) {
      int rn = wc * 64 + n * 16 + la;
      bfr[n] = *(const bf16x8*)&Bs[cur * 4096 + rn * 32 + ((lb ^ (rn & 3)) * 8)];
    }
    #pragma unroll
    for (int m = 0; m < 4; ++m)
      #pragma unroll
      for (int n = 0; n < 4; ++n)
        acc[m][n] = __builtin_amdgcn_mfma_f32_16x16x32_bf16(af[m], bfr[n], acc[m][n], 0, 0, 0);
    if (ks < 6) writeA(cur ^ 1);
    __syncthreads();   // full drain — safe; TLP across 4 blocks/CU hides it
  }

  // epilogue: two N-half passes through the aliased transpose buffer
  const int rrow = tid >> 1, rch = tid & 1;
  const int rb = bbase + rrow;
  const int rcap = caps[rb * T + tblk];
  const float* __restrict__ cbase = Cproj + (dir * 4 + rcap) * 512;
  u16* __restrict__ rop = xp + ((size_t)tblk * NB + rb) * 512;

  #pragma unroll
  for (int pass = 0; pass < 2; ++pass) {
    if (wc == pass) {
      #pragma unroll
      for (int m = 0; m < 4; ++m)
        #pragma unroll
        for (int n = 0; n < 4; ++n)
          *(f32x4*)&Cls[n * 16 + la][wr * 64 + m * 16 + lb * 4] = acc[m][n];
    }
    __syncthreads();
    int colp0 = n0 + pass * 64 + rch * 32;
    #pragma unroll
    for (int s = 0; s < 4; ++s) {
      u16x8 o;
      #pragma unroll
      for (int e = 0; e < 8; ++e) {
        int cl = rch * 32 + s * 8 + e;
        o[e] = f2bf(Cls[cl][rrow] + cbase[colp0 + s * 8 + e]);
      }
      *(u16x8*)(rop + colp0 + s * 8) = o;
    }
    __syncthreads();
  }
}

// ------------------------------------------------------------ LSTM ----------
// 8 waves (512 thr), 32 blocks (16 batch rows x 2 dir).
template <int PAR>
__device__ __forceinline__ void lstm_step(
    int t, int dir, int la, int lb, int j,
    const u16* __restrict__ xpd, int voff0, int voff1, int voff2, int voff3,
    const bf16x8 (&bfrag)[4][4], u16* __restrict__ hbuf,
    u16x4 (&xc)[4],            // data for t (consume)
    u16x4 (&xg)[4],            // load target for t+2
    f32x4& cst, f32x4& hl) {
  // A fragments (h_prev) from swizzled LDS
  const u16* hb = hbuf + PAR * 2048;
  const int swz = (la & 7) << 3;
  bf16x8 afr[4];
  #pragma unroll
  for (int kk = 0; kk < 4; ++kk)
    afr[kk] = *(const bf16x8*)(hb + ((la * 128 + kk * 32 + lb * 8) ^ swz));

  // issue xp loads for t+2 (linear stream, 2-step prefetch)
  {
    int ts = t + 2; if (ts > T - 1) ts = T - 1;
    int tt = dir ? (T - 1 - ts) : ts;
    const u16* p = xpd + (size_t)tt * (NB * 512);
    xg[0] = *(const u16x4*)(p + voff0);
    xg[1] = *(const u16x4*)(p + voff1);
    xg[2] = *(const u16x4*)(p + voff2);
    xg[3] = *(const u16x4*)(p + voff3);
  }

  // accumulators = x-projection (pre-scaled, bias+cap folded)
  f32x4 acc0, acc1, acc2, acc3;
  #pragma unroll
  for (int r = 0; r < 4; ++r) {
    acc0[r] = bf2f(xc[r][0]);
    acc1[r] = bf2f(xc[r][1]);
    acc2[r] = bf2f(xc[r][2]);
    acc3[r] = bf2f(xc[r][3]);
  }
  // gates += h_prev @ Wh (pre-scaled)
  __builtin_amdgcn_s_setprio(1);
  #pragma unroll
  for (int kk = 0; kk < 4; ++kk) {
    acc0 = __builtin_amdgcn_mfma_f32_16x16x32_bf16(afr[kk], bfrag[0][kk], acc0, 0, 0, 0);
    acc1 = __builtin_amdgcn_mfma_f32_16x16x32_bf16(afr[kk], bfrag[1][kk], acc1, 0, 0, 0);
    acc2 = __builtin_amdgcn_mfma_f32_16x16x32_bf16(afr[kk], bfrag[2][kk], acc2, 0, 0, 0);
    acc3 = __builtin_amdgcn_mfma_f32_16x16x32_bf16(afr[kk], bfrag[3][kk], acc3, 0, 0, 0);
  }
  __builtin_amdgcn_s_setprio(0);
  // cell update — 7 trans/cell: 5 ex2 + 2 rcp (c-update rcps fused over
  // a common denominator); write h_new to other buffer (swizzled)
  u16* ho = hbuf + (PAR ^ 1) * 2048;
  #pragma unroll
  for (int r = 0; r < 4; ++r) {
    float ei = ex2_(acc0[r]);
    float ej = ex2_(acc1[r]);
    float ef = ex2_(acc2[r]);
    float eo = ex2_(acc3[r]);
    float pij = (1.f + ei) * (1.f + ej);
    float pf  = 1.f + ef;
    float num = cst[r] * pij + (ej - 1.f) * pf;
    float cn  = num * rcp_(pij * pf);
    cst[r] = cn;
    float E = ex2_(2.f * LOG2E * cn);
    float hn = (E - 1.f) * rcp_((1.f + eo) * (1.f + E));
    hl[r] = hn;
    int row = lb * 4 + r;
    ho[(row * 128 + j) ^ ((row & 7) << 3)] = f2bf(hn);
  }
  // LDS-only drain + raw barrier: vmcnt NOT drained, xp loads stay in flight
  __builtin_amdgcn_sched_barrier(0);
  asm volatile("s_waitcnt lgkmcnt(0)");
  __builtin_amdgcn_s_barrier();
  __builtin_amdgcn_sched_barrier(0);
}

__global__ __launch_bounds__(512, 1) void lstm_kernel(
    const u16* __restrict__ XP, const float* __restrict__ Wfw,
    const float* __restrict__ Wbw, float* __restrict__ rnn) {
  const int dir = blockIdx.x & 1;
  const int chunk = blockIdx.x >> 1;
  const int b0 = chunk * 16;
  const u16* __restrict__ xpd = XP + (size_t)dir * T * NB * 512;
  const float* __restrict__ W = dir ? Wbw : Wfw;

  const int tid = threadIdx.x;
  const int w = tid >> 6, l = tid & 63, la = l & 15, lb = l >> 4;
  const int j = w * 16 + la;

  const int voff0 = (b0 + lb * 4 + 0) * 512 + j * 4;
  const int voff1 = (b0 + lb * 4 + 1) * 512 + j * 4;
  const int voff2 = (b0 + lb * 4 + 2) * 512 + j * 4;
  const int voff3 = (b0 + lb * 4 + 3) * 512 + j * 4;

  // Wh fragments (pre-scaled): col = g*128 + j, k = kk*32 + lb*8 + r
  bf16x8 bfrag[4][4];
  #pragma unroll
  for (int g = 0; g < 4; ++g) {
    #pragma unroll
    for (int kk = 0; kk < 4; ++kk) {
      short8 t8;
      #pragma unroll
      for (int r = 0; r < 8; ++r) {
        int k = kk * 32 + lb * 8 + r;
        t8[r] = (short)f2bf(W[(203 + k) * 512 + g * 128 + j] * gsc(g));
      }
      bfrag[g][kk] = __builtin_bit_cast(bf16x8, t8);
    }
  }

  __shared__ u16 hbuf[2 * 16 * 128];
  for (int i = tid; i < 2 * 16 * 128; i += 512) hbuf[i] = 0;

  f32x4 cst = {0.f, 0.f, 0.f, 0.f};
  f32x4 hl  = {0.f, 0.f, 0.f, 0.f};

  u16x4 xA[4], xB[4], xC[4], xD[4];
  {
    int tt0 = dir ? (T - 1) : 0;
    int tt1 = dir ? (T - 2) : 1;
    const u16* p0 = xpd + (size_t)tt0 * (NB * 512);
    const u16* p1 = xpd + (size_t)tt1 * (NB * 512);
    xA[0] = *(const u16x4*)(p0 + voff0); xA[1] = *(const u16x4*)(p0 + voff1);
    xA[2] = *(const u16x4*)(p0 + voff2); xA[3] = *(const u16x4*)(p0 + voff3);
    xB[0] = *(const u16x4*)(p1 + voff0); xB[1] = *(const u16x4*)(p1 + voff1);
    xB[2] = *(const u16x4*)(p1 + voff2); xB[3] = *(const u16x4*)(p1 + voff3);
  }
  __syncthreads();

  #pragma unroll 1
  for (int tq = 0; tq < T / 4; ++tq) {
    int t0 = 4 * tq;
    lstm_step<0>(t0,     dir, la, lb, j, xpd, voff0, voff1, voff2, voff3,
                 bfrag, hbuf, xA, xC, cst, hl);
    lstm_step<1>(t0 + 1, dir, la, lb, j, xpd, voff0, voff1, voff2, voff3,
                 bfrag, hbuf, xB, xD, cst, hl);
    lstm_step<0>(t0 + 2, dir, la, lb, j, xpd, voff0, voff1, voff2, voff3,
                 bfrag, hbuf, xC, xA, cst, hl);
    lstm_step<1>(t0 + 3, dir, la, lb, j, xpd, voff0, voff1, voff2, voff3,
                 bfrag, hbuf, xD, xB, cst, hl);
  }

  #pragma unroll
  for (int r = 0; r < 4; ++r)
    rnn[(size_t)(b0 + lb * 4 + r) * 256 + dir * 128 + j] = hl[r];
}

// ------------------------------------------------------------ head ----------
__global__ void head_kernel(const float* __restrict__ rnn, const float* __restrict__ W1,
                            const float* __restrict__ b1, const float* __restrict__ W2,
                            const float* __restrict__ b2, float* __restrict__ out) {
  int b = blockIdx.x;
  int jj = threadIdx.x;  // 64 threads
  __shared__ float d1[64];
  float acc = b1[jj];
  const float* r = rnn + b * 256;
  #pragma unroll 4
  for (int k = 0; k < 256; ++k) acc += r[k] * W1[k * 64 + jj];
  d1[jj] = acc > 0.f ? acc : (__expf(acc) - 1.f);
  __syncthreads();
  if (jj < 6) {
    float a2 = b2[jj];
    #pragma unroll 8
    for (int k = 0; k < 64; ++k) a2 += d1[k] * W2[k * 6 + jj];
    out[b * 6 + jj] = rcp_(1.f + __expf(-a2));
  }
}

// ------------------------------------------------------------ launch --------
extern "C" void kernel_launch(void* const* d_in, const int* in_sizes, int n_in,
                              void* d_out, int out_size, void* d_ws, size_t ws_size,
                              hipStream_t stream) {
  (void)in_sizes; (void)n_in; (void)out_size; (void)ws_size;
  const int*   words    = (const int*)  d_in[0];
  const int*   caps     = (const int*)  d_in[1];
  const float* word_emb = (const float*)d_in[2];
  const float* cap_emb  = (const float*)d_in[3];
  const float* Wfw      = (const float*)d_in[4];
  const float* bfw      = (const float*)d_in[5];
  const float* Wbw      = (const float*)d_in[6];
  const float* bbw      = (const float*)d_in[7];
  const float* W1       = (const float*)d_in[8];
  const float* b1       = (const float*)d_in[9];
  const float* W2       = (const float*)d_in[10];
  const float* b2       = (const float*)d_in[11];
  float* out = (float*)d_out;

  char* base = (char*)d_ws;
  size_t off = 0;
  auto alloc = [&](size_t bytes) {
    char* q = base + off;
    off = (off + bytes + 255) & ~(size_t)255;
    return q;
  };
  u16*   XP     = (u16*)  alloc((size_t)2 * T * NB * 512 * 2);   // 262.1 MB
  u16*   Bt     = (u16*)  alloc((size_t)2 * 512 * KPAD * 2);
  float* Cproj  = (float*)alloc((size_t)2 * 4 * 512 * 4);
  float* rnn    = (float*)alloc((size_t)256 * 256 * 4);
  // total ~262.9 MB == R7-proven budget.

  hipLaunchKernelGGL(prep_kernel, dim3(256), dim3(256), 0, stream,
                     cap_emb, Wfw, bfw, Wbw, bbw, Cproj, Bt);
  hipLaunchKernelGGL(xproj_kernel, dim3(8000), dim3(256), 0, stream,
                     words, caps, word_emb, Bt, Cproj, XP);
  hipLaunchKernelGGL(lstm_kernel, dim3(32), dim3(512), 0, stream,
                     XP, Wfw, Wbw, rnn);
  hipLaunchKernelGGL(head_kernel, dim3(256), dim3(64), 0, stream,
                     rnn, W1, b1, W2, b2, out);
}